// Round 17
// baseline (247.360 us; speedup 1.0000x reference)
//
#include <hip/hip_runtime.h>
#include <hip/hip_bf16.h>
#include <math.h>

#define SEQ    2048
#define DH     64
#define EMB    512
#define INDIM  512
#define NHEADS 8
#define BATCH  4
#define MTOT   (BATCH * SEQ)   // 8192

typedef __attribute__((ext_vector_type(8))) short bf16x8;   // 8 bf16 = 4 VGPR
typedef __attribute__((ext_vector_type(4))) float f32x4;

__device__ __forceinline__ ushort f2bf(float x) {
  union { float f; unsigned u; } v; v.f = x;
  unsigned r = v.u + 0x7FFFu + ((v.u >> 16) & 1u);   // RNE
  return (ushort)(r >> 16);
}

// packed f32x2 -> bf16x2 (single HW op)
__device__ __forceinline__ unsigned cvt_pk_bf16(float lo, float hi) {
  unsigned r;
  asm("v_cvt_pk_bf16_f32 %0, %1, %2" : "=v"(r) : "v"(lo), "v"(hi));
  return r;
}

// raw v_exp_f32 (exp2); args bounded (static-max softmax)
__device__ __forceinline__ float fast_exp2(float x) {
  float r;
  asm("v_exp_f32 %0, %1" : "=v"(r) : "v"(x));
  return r;
}

// v_permlane32_swap_b32: after: x = [x.h0, y.h0], y = [x.h1, y.h1] (lane halves)
__device__ __forceinline__ void permswap32(unsigned &x, unsigned &y) {
  asm("v_permlane32_swap_b32 %0, %1" : "+v"(x), "+v"(y));
}

// ---------------------------------------------------------------------------
// f32 -> bf16 conversion, 8 elems/thread
// ---------------------------------------------------------------------------
__global__ __launch_bounds__(256) void conv_bf16(const float* __restrict__ src,
                                                 ushort* __restrict__ dst, int n8) {
  const int i = blockIdx.x * 256 + threadIdx.x;
  if (i >= n8) return;
  const float4 a = ((const float4*)src)[i * 2];
  const float4 b = ((const float4*)src)[i * 2 + 1];
  uint4 o;
  o.x = cvt_pk_bf16(a.x, a.y);
  o.y = cvt_pk_bf16(a.z, a.w);
  o.z = cvt_pk_bf16(b.x, b.y);
  o.w = cvt_pk_bf16(b.z, b.w);
  ((uint4*)dst)[i] = o;
}

// 4 weight matrices in one launch (blockIdx.y selects)
__global__ __launch_bounds__(256) void conv_bf16_w4(
    const float* __restrict__ w0, const float* __restrict__ w1,
    const float* __restrict__ w2, const float* __restrict__ w3,
    ushort* __restrict__ dst, int n8per) {
  const int i = blockIdx.x * 256 + threadIdx.x;
  if (i >= n8per) return;
  const float* src = (blockIdx.y == 0) ? w0 : (blockIdx.y == 1) ? w1
                   : (blockIdx.y == 2) ? w2 : w3;
  ushort* d = dst + (size_t)blockIdx.y * n8per * 8;
  const float4 a = ((const float4*)src)[i * 2];
  const float4 b = ((const float4*)src)[i * 2 + 1];
  uint4 o;
  o.x = cvt_pk_bf16(a.x, a.y);
  o.y = cvt_pk_bf16(a.z, a.w);
  o.z = cvt_pk_bf16(b.x, b.y);
  o.w = cvt_pk_bf16(b.z, b.w);
  ((uint4*)d)[i] = o;
}

// ---------------------------------------------------------------------------
// MFMA GEMM, m97 structure, BK=32, 4 waves, global_load_lds width 16.
// MODE 0: 128x128 tile. Fused QKV (N=1536). which=bn>>9: 0->Q (pre-scaled
//         by 0.125*log2e), 1->K bf16 [B,H,N,Dh] (coalesced via LDS re-stage);
//         2->V^T bf16 [B,H,Dh,N] via LDS transpose.
// MODE 1: 64x128 tile (grid 512 = 2 blocks/CU). f32 out [M][EMB]+bias.
// ---------------------------------------------------------------------------
template <int MODE>
__global__ __launch_bounds__(256) void mfma_gemm(
    const ushort* __restrict__ A, const ushort* __restrict__ W,
    const float* __restrict__ b0, const float* __restrict__ b1,
    const float* __restrict__ b2,
    ushort* __restrict__ outQ, ushort* __restrict__ outK,
    ushort* __restrict__ outVT, float* __restrict__ outF) {
  constexpr int BM = (MODE == 0) ? 128 : 64;
  constexpr int MF = (MODE == 0) ? 4 : 2;       // m-frags per wave
  __shared__ __align__(16) char smem[MODE == 0 ? 35840 : 12288];
  ushort* As = (ushort*)smem;                         // [BM][32]
  ushort* Bs = (ushort*)(smem + (MODE == 0 ? 8192 : 4096));  // [128][32]
  ushort* Tl = (ushort*)smem;            // V epilogue transpose [128][140]
  ushort* Tl2 = (ushort*)smem;           // Q/K epilogue stage [128][136]

  const int bm = blockIdx.x * BM;
  const int bn = blockIdx.y * 128;
  const int tid = threadIdx.x;
  const int wave = tid >> 6, lane = tid & 63;
  const int g = lane >> 4, ln = lane & 15;
  const int wr = wave >> 1, wc = wave & 1;

  f32x4 acc[MF][4];
#pragma unroll
  for (int m = 0; m < MF; ++m)
#pragma unroll
    for (int n = 0; n < 4; ++n) acc[m][n] = (f32x4){0.f, 0.f, 0.f, 0.f};

  const size_t a_base = (size_t)(bm + wave * 16 + (lane >> 2)) * INDIM + (lane & 3) * 8;
  const size_t b_base = (size_t)(bn + wave * 16 + (lane >> 2)) * INDIM + (lane & 3) * 8;
  ushort* ldsA0 = As + wave * 512;
  ushort* ldsA1 = As + 2048 + wave * 512;
  ushort* ldsB0 = Bs + wave * 512;
  ushort* ldsB1 = Bs + 2048 + wave * 512;

  for (int k0 = 0; k0 < INDIM; k0 += 32) {
    __syncthreads();
    __builtin_amdgcn_global_load_lds(
        (const __attribute__((address_space(1))) void*)(A + a_base + k0),
        (__attribute__((address_space(3))) void*)ldsA0, 16, 0, 0);
    if (MODE == 0)
      __builtin_amdgcn_global_load_lds(
          (const __attribute__((address_space(1))) void*)(A + a_base + 64 * INDIM + k0),
          (__attribute__((address_space(3))) void*)ldsA1, 16, 0, 0);
    __builtin_amdgcn_global_load_lds(
        (const __attribute__((address_space(1))) void*)(W + b_base + k0),
        (__attribute__((address_space(3))) void*)ldsB0, 16, 0, 0);
    __builtin_amdgcn_global_load_lds(
        (const __attribute__((address_space(1))) void*)(W + b_base + 64 * INDIM + k0),
        (__attribute__((address_space(3))) void*)ldsB1, 16, 0, 0);
    __syncthreads();

    bf16x8 af[MF], bfv[4];
#pragma unroll
    for (int m = 0; m < MF; ++m)
      af[m] = *(const bf16x8*)&As[((MODE == 0 ? 64 : 32) * wr + 16 * m + ln) * 32 + 8 * g];
#pragma unroll
    for (int n = 0; n < 4; ++n)
      bfv[n] = *(const bf16x8*)&Bs[(64 * wc + 16 * n + ln) * 32 + 8 * g];
#pragma unroll
    for (int m = 0; m < MF; ++m)
#pragma unroll
      for (int n = 0; n < 4; ++n)
        acc[m][n] = __builtin_amdgcn_mfma_f32_16x16x32_bf16(af[m], bfv[n], acc[m][n], 0, 0, 0);
  }

  // ---- epilogue ----
  if (MODE == 1) {
#pragma unroll
    for (int n = 0; n < 4; ++n) {
      const int e = bn + 64 * wc + 16 * n + ln;
      const float bv = b0[e];
#pragma unroll
      for (int m = 0; m < MF; ++m)
#pragma unroll
        for (int r = 0; r < 4; ++r) {
          const int row = bm + 32 * wr + 16 * m + 4 * g + r;
          outF[(size_t)row * EMB + e] = acc[m][n][r] + bv;
        }
    }
    return;
  }

  const int which = bn >> 9;
  const float* bias = (which == 0) ? b0 : (which == 1) ? b1 : b2;

  if (which < 2) {
    // Q gets the softmax scale folded in (log2 domain): 0.125 * log2(e)
    const float scl = (which == 0) ? 0.18033688f : 1.0f;
    ushort* dst = (which == 0) ? outQ : outK;
    __syncthreads();   // As/Bs reads done; reuse smem as Tl2[128][136]
#pragma unroll
    for (int n = 0; n < 4; ++n) {
      const int cl = 64 * wc + 16 * n + ln;
      const float bv = bias[(bn & 511) + cl];
#pragma unroll
      for (int m = 0; m < 4; ++m)
#pragma unroll
        for (int r = 0; r < 4; ++r) {
          const int rl = 64 * wr + 16 * m + 4 * g + r;
          Tl2[rl * 136 + cl] = f2bf((acc[m][n][r] + bv) * scl);
        }
    }
    __syncthreads();
    // coalesced write-out: 256 segments of 128B (row rl x head-half)
#pragma unroll
    for (int j = 0; j < 8; ++j) {
      const int cid = j * 256 + tid;      // 0..2047
      const int seg = cid >> 3;           // 0..255
      const int l8 = cid & 7;
      const int rl = seg >> 1, half = seg & 1;
      const int row = bm + rl;
      const int b = row >> 11, nn = row & (SEQ - 1);
      const int h = ((bn & 511) >> 6) + half;
      const bf16x8 v = *(const bf16x8*)&Tl2[rl * 136 + half * 64 + l8 * 8];
      *(bf16x8*)&dst[(((size_t)(b * NHEADS + h) * SEQ) + nn) * DH + l8 * 8] = v;
    }
  } else {
    // V: transpose through LDS, write V^T [B,H,Dh,N]
    __syncthreads();
#pragma unroll
    for (int n = 0; n < 4; ++n) {
      const int cl = 64 * wc + 16 * n + ln;
      const float bv = bias[(bn & 511) + cl];
#pragma unroll
      for (int m = 0; m < 4; ++m)
#pragma unroll
        for (int r = 0; r < 4; ++r) {
          const int rl = 64 * wr + 16 * m + 4 * g + r;
          Tl[cl * 140 + rl] = f2bf(acc[m][n][r] + bv);
        }
    }
    __syncthreads();
    const int c = tid >> 1;
    const int rh = (tid & 1) * 64;
    const int e = (bn & 511) + c;
    const int h = e >> 6, d = e & 63;
    const int b = bm >> 11;
    const int nn0 = (bm & (SEQ - 1)) + rh;
    ushort* drow = outVT + (((size_t)(b * NHEADS + h) * DH) + d) * SEQ + nn0;
#pragma unroll
    for (int j = 0; j < 8; ++j)
      *(bf16x8*)&drow[j * 8] = *(const bf16x8*)&Tl[c * 140 + rh + j * 8];
  }
}

// ---------------------------------------------------------------------------
// MFMA flash attention: IN-BLOCK kv-split x2 built from the R12-VERBATIM loop.
// 512 threads = 8 waves; half = tid>>8 processes kv in [half*1024, +1024)
// with the R12-verified body (kv-step 64, double-buffered per-half LDS,
// merged-phase A/B, 1 barrier/iter, 16 iters) on buffers Kl[half]/Vl[half].
// 512 blocks x 8 waves = 4096 waves = 4 waves/SIMD (R15 ran 2/SIMD,
// latency-bound: all pipes <50% with ~4x wall/issue gap).
// Combine: half 0 writes f32 acc + lane-local denominators to an LDS overlay
// (dead K/V space), barrier, half 1 adds its partials, normalizes, stores
// bf16 -- deterministic. LDS 73.7KB -> 2 blocks/CU.
// Denominator via ones-MFMA, in-register P (pi-permuted K staging + cvt_pk +
// permlane32_swap), static-max exp2 softmax (Q pre-scaled by 0.125*log2e),
// XCD swizzle, bf16 O.
// ---------------------------------------------------------------------------
__global__ __launch_bounds__(512, 4) void attn_mfma(const ushort* __restrict__ Q,
                                                    const ushort* __restrict__ K,
                                                    const ushort* __restrict__ VT,
                                                    ushort* __restrict__ O) {
  __shared__ __align__(16) ushort Kl[2][2][64 * 72];  // [half][buf][kv(pi)][d]
  __shared__ __align__(16) ushort Vl[2][2][64 * 72];  // [half][buf][d][kv]

  const int tid = threadIdx.x;
  const int half = tid >> 8;            // kv half
  const int ltid = tid & 255;           // local tid within half
  const int wave = ltid >> 6, lane = ltid & 63;
  const int g = lane >> 4, ln = lane & 15;

  // XCD swizzle over 512 wgs: swz = (orig%8)*64 + orig/8 (bijective; 4 bh/XCD)
  const int orig = blockIdx.x;
  const int swz = (orig & 7) * 64 + (orig >> 3);
  const int bh = swz >> 4;            // 0..31
  const int qx = swz & 15;            // 0..15
  const int qbase = qx * 128 + wave * 32;
  const int kvbase = half << 10;      // 0 or 1024

  const ushort* Qb = Q + ((size_t)bh * SEQ + qbase) * DH;
  const ushort* Kb = K + (size_t)bh * SEQ * DH;
  const ushort* Vb = VT + (size_t)bh * DH * SEQ;

  const bf16x8 qfA0 = *(const bf16x8*)&Qb[ln * DH + 8 * g];
  const bf16x8 qfA1 = *(const bf16x8*)&Qb[ln * DH + 32 + 8 * g];
  const bf16x8 qfB0 = *(const bf16x8*)&Qb[(16 + ln) * DH + 8 * g];
  const bf16x8 qfB1 = *(const bf16x8*)&Qb[(16 + ln) * DH + 32 + 8 * g];

  // ones B-fragment for the denominator MFMA (bf16 1.0 = 0x3F80)
  bf16x8 vones;
#pragma unroll
  for (int i = 0; i < 8; ++i) vones[i] = (short)0x3F80;

  f32x4 oaccA[4], oaccB[4];
  f32x4 oaccDA = (f32x4){0.f, 0.f, 0.f, 0.f};
  f32x4 oaccDB = (f32x4){0.f, 0.f, 0.f, 0.f};
#pragma unroll
  for (int t = 0; t < 4; ++t) {
    oaccA[t] = (f32x4){0.f, 0.f, 0.f, 0.f};
    oaccB[t] = (f32x4){0.f, 0.f, 0.f, 0.f};
  }

  const int skv = ltid >> 3, sd = (ltid & 7) * 8;   // K staging (rows skv, skv+32)
  const int dt = ltid >> 2, kc = (ltid & 3) * 8;    // V staging
  // pi-permuted LDS rows for K: XOR 12 where bit2^bit3 (swaps rows 4-7 <-> 8-11)
  const int pr0 = skv ^ (((((skv >> 2) ^ (skv >> 3)) & 1)) * 12);
  const int s32 = skv + 32;
  const int pr1 = s32 ^ (((((s32 >> 2) ^ (s32 >> 3)) & 1)) * 12);

  // ---- preload: tile 0 -> regs -> buf0; tile 1 -> regs ----
  bf16x8 k0v = *(const bf16x8*)&Kb[(size_t)(kvbase + skv) * DH + sd];
  bf16x8 k1v = *(const bf16x8*)&Kb[(size_t)(kvbase + 32 + skv) * DH + sd];
  bf16x8 v0v = *(const bf16x8*)&Vb[(size_t)dt * SEQ + kvbase + kc];
  bf16x8 v1v = *(const bf16x8*)&Vb[(size_t)dt * SEQ + kvbase + 32 + kc];
  *(bf16x8*)&Kl[half][0][pr0 * 72 + sd] = k0v;
  *(bf16x8*)&Kl[half][0][pr1 * 72 + sd] = k1v;
  *(bf16x8*)&Vl[half][0][dt * 72 + kc] = v0v;
  *(bf16x8*)&Vl[half][0][dt * 72 + 32 + kc] = v1v;
  k0v = *(const bf16x8*)&Kb[(size_t)(kvbase + 64 + skv) * DH + sd];
  k1v = *(const bf16x8*)&Kb[(size_t)(kvbase + 96 + skv) * DH + sd];
  v0v = *(const bf16x8*)&Vb[(size_t)dt * SEQ + kvbase + 64 + kc];
  v1v = *(const bf16x8*)&Vb[(size_t)dt * SEQ + kvbase + 96 + kc];
  asm volatile("s_waitcnt lgkmcnt(0)" ::: "memory");
  __builtin_amdgcn_s_barrier();

  for (int it = 0; it < 16; ++it) {
    const int cur = it & 1;
    const ushort* Kc = Kl[half][cur];
    const ushort* Vc = Vl[half][cur];

    // stage tile it+1 into the other buffer (regs hold it+1)
    if (it < 15) {
      ushort* Kn = Kl[half][cur ^ 1];
      ushort* Vn = Vl[half][cur ^ 1];
      *(bf16x8*)&Kn[pr0 * 72 + sd] = k0v;
      *(bf16x8*)&Kn[pr1 * 72 + sd] = k1v;
      *(bf16x8*)&Vn[dt * 72 + kc] = v0v;
      *(bf16x8*)&Vn[dt * 72 + 32 + kc] = v1v;
    }
    // prefetch tile it+2 (clamped; redundant tail loads harmless)
    {
      const int nxt = kvbase + ((it + 2 < 16) ? (it + 2) * 64 : 15 * 64);
      k0v = *(const bf16x8*)&Kb[(size_t)(nxt + skv) * DH + sd];
      k1v = *(const bf16x8*)&Kb[(size_t)(nxt + 32 + skv) * DH + sd];
      v0v = *(const bf16x8*)&Vb[(size_t)dt * SEQ + nxt + kc];
      v1v = *(const bf16x8*)&Vb[(size_t)dt * SEQ + nxt + 32 + kc];
    }

    // ---- shared fragments, read ONCE, reused by both q-groups ----
    bf16x8 ka[4][2], vb[2][4];
#pragma unroll
    for (int t = 0; t < 4; ++t) {
      ka[t][0] = *(const bf16x8*)&Kc[(16 * t + ln) * 72 + 8 * g];
      ka[t][1] = *(const bf16x8*)&Kc[(16 * t + ln) * 72 + 32 + 8 * g];
    }
#pragma unroll
    for (int c = 0; c < 2; ++c)
#pragma unroll
      for (int t = 0; t < 4; ++t)
        vb[c][t] = *(const bf16x8*)&Vc[(16 * t + ln) * 72 + 32 * c + 8 * g];

    // ---- QK^T, BOTH groups in one batch (8 independent acc chains) ----
    f32x4 sA0 = (f32x4){0.f, 0.f, 0.f, 0.f};
    f32x4 sA1 = sA0, sA2 = sA0, sA3 = sA0;
    f32x4 sB0 = sA0, sB1 = sA0, sB2 = sA0, sB3 = sA0;
    __builtin_amdgcn_s_setprio(1);
    sA0 = __builtin_amdgcn_mfma_f32_16x16x32_bf16(ka[0][0], qfA0, sA0, 0, 0, 0);
    sB0 = __builtin_amdgcn_mfma_f32_16x16x32_bf16(ka[0][0], qfB0, sB0, 0, 0, 0);
    sA1 = __builtin_amdgcn_mfma_f32_16x16x32_bf16(ka[1][0], qfA0, sA1, 0, 0, 0);
    sB1 = __builtin_amdgcn_mfma_f32_16x16x32_bf16(ka[1][0], qfB0, sB1, 0, 0, 0);
    sA2 = __builtin_amdgcn_mfma_f32_16x16x32_bf16(ka[2][0], qfA0, sA2, 0, 0, 0);
    sB2 = __builtin_amdgcn_mfma_f32_16x16x32_bf16(ka[2][0], qfB0, sB2, 0, 0, 0);
    sA3 = __builtin_amdgcn_mfma_f32_16x16x32_bf16(ka[3][0], qfA0, sA3, 0, 0, 0);
    sB3 = __builtin_amdgcn_mfma_f32_16x16x32_bf16(ka[3][0], qfB0, sB3, 0, 0, 0);
    sA0 = __builtin_amdgcn_mfma_f32_16x16x32_bf16(ka[0][1], qfA1, sA0, 0, 0, 0);
    sB0 = __builtin_amdgcn_mfma_f32_16x16x32_bf16(ka[0][1], qfB1, sB0, 0, 0, 0);
    sA1 = __builtin_amdgcn_mfma_f32_16x16x32_bf16(ka[1][1], qfA1, sA1, 0, 0, 0);
    sB1 = __builtin_amdgcn_mfma_f32_16x16x32_bf16(ka[1][1], qfB1, sB1, 0, 0, 0);
    sA2 = __builtin_amdgcn_mfma_f32_16x16x32_bf16(ka[2][1], qfA1, sA2, 0, 0, 0);
    sB2 = __builtin_amdgcn_mfma_f32_16x16x32_bf16(ka[2][1], qfB1, sB2, 0, 0, 0);
    sA3 = __builtin_amdgcn_mfma_f32_16x16x32_bf16(ka[3][1], qfA1, sA3, 0, 0, 0);
    sB3 = __builtin_amdgcn_mfma_f32_16x16x32_bf16(ka[3][1], qfB1, sB3, 0, 0, 0);
    __builtin_amdgcn_s_setprio(0);

    // ---- P = exp2(S), BOTH groups (32 independent trans ops) ----
    float pA0[4], pA1[4], pA2[4], pA3[4];
    float pB0[4], pB1[4], pB2[4], pB3[4];
#pragma unroll
    for (int r = 0; r < 4; ++r) {
      pA0[r] = fast_exp2(sA0[r]);
      pA1[r] = fast_exp2(sA1[r]);
      pA2[r] = fast_exp2(sA2[r]);
      pA3[r] = fast_exp2(sA3[r]);
      pB0[r] = fast_exp2(sB0[r]);
      pB1[r] = fast_exp2(sB1[r]);
      pB2[r] = fast_exp2(sB2[r]);
      pB3[r] = fast_exp2(sB3[r]);
    }

    // ---- pack + permlane -> PV A-fragments, BOTH groups (no LDS) ----
    unsigned aa0 = cvt_pk_bf16(pA0[0], pA0[1]);
    unsigned aa2 = cvt_pk_bf16(pA1[0], pA1[1]);
    unsigned aa1 = cvt_pk_bf16(pA0[2], pA0[3]);
    unsigned aa3 = cvt_pk_bf16(pA1[2], pA1[3]);
    permswap32(aa0, aa2);
    permswap32(aa1, aa3);
    unsigned ab0 = cvt_pk_bf16(pA2[0], pA2[1]);
    unsigned ab2 = cvt_pk_bf16(pA3[0], pA3[1]);
    unsigned ab1 = cvt_pk_bf16(pA2[2], pA2[3]);
    unsigned ab3 = cvt_pk_bf16(pA3[2], pA3[3]);
    permswap32(ab0, ab2);
    permswap32(ab1, ab3);
    unsigned ba0 = cvt_pk_bf16(pB0[0], pB0[1]);
    unsigned ba2 = cvt_pk_bf16(pB1[0], pB1[1]);
    unsigned ba1 = cvt_pk_bf16(pB0[2], pB0[3]);
    unsigned ba3 = cvt_pk_bf16(pB1[2], pB1[3]);
    permswap32(ba0, ba2);
    permswap32(ba1, ba3);
    unsigned bb0 = cvt_pk_bf16(pB2[0], pB2[1]);
    unsigned bb2 = cvt_pk_bf16(pB3[0], pB3[1]);
    unsigned bb1 = cvt_pk_bf16(pB2[2], pB2[3]);
    unsigned bb3 = cvt_pk_bf16(pB3[2], pB3[3]);
    permswap32(bb0, bb2);
    permswap32(bb1, bb3);
    union { unsigned u[4]; bf16x8 v; } paA0, paA1, paB0, paB1;
    paA0.u[0] = aa0; paA0.u[1] = aa1; paA0.u[2] = aa2; paA0.u[3] = aa3;
    paA1.u[0] = ab0; paA1.u[1] = ab1; paA1.u[2] = ab2; paA1.u[3] = ab3;
    paB0.u[0] = ba0; paB0.u[1] = ba1; paB0.u[2] = ba2; paB0.u[3] = ba3;
    paB1.u[0] = bb0; paB1.u[1] = bb1; paB1.u[2] = bb2; paB1.u[3] = bb3;

    // ---- PV + denominators, BOTH groups in one MFMA batch ----
    __builtin_amdgcn_s_setprio(1);
#pragma unroll
    for (int t = 0; t < 4; ++t) {
      oaccA[t] = __builtin_amdgcn_mfma_f32_16x16x32_bf16(paA0.v, vb[0][t], oaccA[t], 0, 0, 0);
      oaccB[t] = __builtin_amdgcn_mfma_f32_16x16x32_bf16(paB0.v, vb[0][t], oaccB[t], 0, 0, 0);
      oaccA[t] = __builtin_amdgcn_mfma_f32_16x16x32_bf16(paA1.v, vb[1][t], oaccA[t], 0, 0, 0);
      oaccB[t] = __builtin_amdgcn_mfma_f32_16x16x32_bf16(paB1.v, vb[1][t], oaccB[t], 0, 0, 0);
    }
    oaccDA = __builtin_amdgcn_mfma_f32_16x16x32_bf16(paA0.v, vones, oaccDA, 0, 0, 0);
    oaccDB = __builtin_amdgcn_mfma_f32_16x16x32_bf16(paB0.v, vones, oaccDB, 0, 0, 0);
    oaccDA = __builtin_amdgcn_mfma_f32_16x16x32_bf16(paA1.v, vones, oaccDA, 0, 0, 0);
    oaccDB = __builtin_amdgcn_mfma_f32_16x16x32_bf16(paB1.v, vones, oaccDB, 0, 0, 0);
    __builtin_amdgcn_s_setprio(0);

    // single barrier per iter: my ds reads (buf cur) + writes (buf cur^1) done
    asm volatile("s_waitcnt lgkmcnt(0)" ::: "memory");
    __builtin_amdgcn_s_barrier();
  }

  // ---- combine halves through LDS overlay (K/V buffers are dead) ----
  float* Acc = (float*)&Kl[0][0][0];    // [128][68] f32 = 34816B (fits 36864B)
  float* Dl  = (float*)&Vl[0][0][0];    // [128] f32
  __syncthreads();
  if (half == 0) {
#pragma unroll
    for (int t = 0; t < 4; ++t)
#pragma unroll
      for (int r = 0; r < 4; ++r) {
        Acc[(wave * 32 + 4 * g + r) * 68 + 16 * t + ln] = oaccA[t][r];
        Acc[(wave * 32 + 16 + 4 * g + r) * 68 + 16 * t + ln] = oaccB[t][r];
      }
    if (ln == 0) {
#pragma unroll
      for (int r = 0; r < 4; ++r) {
        Dl[wave * 32 + 4 * g + r] = oaccDA[r];
        Dl[wave * 32 + 16 + 4 * g + r] = oaccDB[r];
      }
    }
  }
  __syncthreads();
  if (half == 1) {
    const int b = bh >> 3, h = bh & 7;
#pragma unroll
    for (int r = 0; r < 4; ++r) {
      const int rowA = wave * 32 + 4 * g + r;
      const int rowB = rowA + 16;
      const float irA = 1.0f / (Dl[rowA] + oaccDA[r]);
      const float irB = 1.0f / (Dl[rowB] + oaccDB[r]);
      ushort* opA = O + ((size_t)(b * SEQ) + qx * 128 + rowA) * EMB + h * 64;
      ushort* opB = O + ((size_t)(b * SEQ) + qx * 128 + rowB) * EMB + h * 64;
#pragma unroll
      for (int t = 0; t < 4; ++t) {
        opA[16 * t + ln] = f2bf((Acc[rowA * 68 + 16 * t + ln] + oaccA[t][r]) * irA);
        opB[16 * t + ln] = f2bf((Acc[rowB * 68 + 16 * t + ln] + oaccB[t][r]) * irB);
      }
    }
  }
}

// ---------------------------------------------------------------------------
extern "C" void kernel_launch(void* const* d_in, const int* in_sizes, int n_in,
                              void* d_out, int out_size, void* d_ws, size_t ws_size,
                              hipStream_t stream) {
  const float* q  = (const float*)d_in[0];
  const float* wq = (const float*)d_in[1];
  const float* bq = (const float*)d_in[2];
  const float* wk = (const float*)d_in[3];
  const float* bk = (const float*)d_in[4];
  const float* wv = (const float*)d_in[5];
  const float* bv = (const float*)d_in[6];
  const float* wo = (const float*)d_in[7];
  const float* bo = (const float*)d_in[8];
  float* out = (float*)d_out;

  const size_t XSZ = (size_t)MTOT * INDIM;
  const size_t WSZ = (size_t)EMB * INDIM;
  const size_t QSZ = (size_t)BATCH * NHEADS * SEQ * DH;
  ushort* wsX = (ushort*)d_ws;
  ushort* wsW = wsX + XSZ;
  ushort* wsQ = wsW + 4 * WSZ;
  ushort* wsK = wsQ + QSZ;
  ushort* wsVT = wsK + QSZ;
  ushort* wsA = wsVT + QSZ;   // attn output bf16 [B,N,EMB]

  const dim3 blk(256);

  conv_bf16<<<dim3(XSZ / 8 / 256), blk, 0, stream>>>(q, wsX, XSZ / 8);
  conv_bf16_w4<<<dim3(WSZ / 8 / 256, 4), blk, 0, stream>>>(wq, wk, wv, wo, wsW, WSZ / 8);

  mfma_gemm<0><<<dim3(MTOT / 128, 1536 / 128), blk, 0, stream>>>(
      wsX, wsW, bq, bk, bv, wsQ, wsK, wsVT, nullptr);

  attn_mfma<<<dim3(512), dim3(512), 0, stream>>>(wsQ, wsK, wsVT, wsA);

  mfma_gemm<1><<<dim3(MTOT / 64, EMB / 128), blk, 0, stream>>>(
      wsA, wsW + 3 * WSZ, bo, nullptr, nullptr, nullptr, nullptr, nullptr, out);
}

// Round 18
// 99.323 us; speedup vs baseline: 2.4905x; 2.4905x over previous
//
#include <hip/hip_runtime.h>
#include <hip/hip_bf16.h>
#include <math.h>

#define SEQ    2048
#define DH     64
#define EMB    512
#define INDIM  512
#define NHEADS 8
#define BATCH  4
#define MTOT   (BATCH * SEQ)   // 8192

typedef __attribute__((ext_vector_type(8))) short bf16x8;   // 8 bf16 = 4 VGPR
typedef __attribute__((ext_vector_type(4))) float f32x4;

__device__ __forceinline__ ushort f2bf(float x) {
  union { float f; unsigned u; } v; v.f = x;
  unsigned r = v.u + 0x7FFFu + ((v.u >> 16) & 1u);   // RNE
  return (ushort)(r >> 16);
}

// packed f32x2 -> bf16x2 (single HW op)
__device__ __forceinline__ unsigned cvt_pk_bf16(float lo, float hi) {
  unsigned r;
  asm("v_cvt_pk_bf16_f32 %0, %1, %2" : "=v"(r) : "v"(lo), "v"(hi));
  return r;
}

// raw v_exp_f32 (exp2); args bounded (static-max softmax)
__device__ __forceinline__ float fast_exp2(float x) {
  float r;
  asm("v_exp_f32 %0, %1" : "=v"(r) : "v"(x));
  return r;
}

// v_permlane32_swap_b32: after: x = [x.h0, y.h0], y = [x.h1, y.h1] (lane halves)
__device__ __forceinline__ void permswap32(unsigned &x, unsigned &y) {
  asm("v_permlane32_swap_b32 %0, %1" : "+v"(x), "+v"(y));
}

// ---------------------------------------------------------------------------
// f32 -> bf16 conversion, 8 elems/thread
// ---------------------------------------------------------------------------
__global__ __launch_bounds__(256) void conv_bf16(const float* __restrict__ src,
                                                 ushort* __restrict__ dst, int n8) {
  const int i = blockIdx.x * 256 + threadIdx.x;
  if (i >= n8) return;
  const float4 a = ((const float4*)src)[i * 2];
  const float4 b = ((const float4*)src)[i * 2 + 1];
  uint4 o;
  o.x = cvt_pk_bf16(a.x, a.y);
  o.y = cvt_pk_bf16(a.z, a.w);
  o.z = cvt_pk_bf16(b.x, b.y);
  o.w = cvt_pk_bf16(b.z, b.w);
  ((uint4*)dst)[i] = o;
}

// 4 weight matrices in one launch (blockIdx.y selects)
__global__ __launch_bounds__(256) void conv_bf16_w4(
    const float* __restrict__ w0, const float* __restrict__ w1,
    const float* __restrict__ w2, const float* __restrict__ w3,
    ushort* __restrict__ dst, int n8per) {
  const int i = blockIdx.x * 256 + threadIdx.x;
  if (i >= n8per) return;
  const float* src = (blockIdx.y == 0) ? w0 : (blockIdx.y == 1) ? w1
                   : (blockIdx.y == 2) ? w2 : w3;
  ushort* d = dst + (size_t)blockIdx.y * n8per * 8;
  const float4 a = ((const float4*)src)[i * 2];
  const float4 b = ((const float4*)src)[i * 2 + 1];
  uint4 o;
  o.x = cvt_pk_bf16(a.x, a.y);
  o.y = cvt_pk_bf16(a.z, a.w);
  o.z = cvt_pk_bf16(b.x, b.y);
  o.w = cvt_pk_bf16(b.z, b.w);
  ((uint4*)d)[i] = o;
}

// ---------------------------------------------------------------------------
// MFMA GEMM, m97 structure, BK=32, 4 waves, global_load_lds width 16.
// MODE 0: 128x128 tile. Fused QKV (N=1536). which=bn>>9: 0->Q (pre-scaled
//         by 0.125*log2e), 1->K bf16 [B,H,N,Dh] (coalesced via LDS re-stage);
//         2->V^T bf16 [B,H,Dh,N] via LDS transpose.
// MODE 1: 64x128 tile (grid 512 = 2 blocks/CU). f32 out [M][EMB]+bias.
// ---------------------------------------------------------------------------
template <int MODE>
__global__ __launch_bounds__(256) void mfma_gemm(
    const ushort* __restrict__ A, const ushort* __restrict__ W,
    const float* __restrict__ b0, const float* __restrict__ b1,
    const float* __restrict__ b2,
    ushort* __restrict__ outQ, ushort* __restrict__ outK,
    ushort* __restrict__ outVT, float* __restrict__ outF) {
  constexpr int BM = (MODE == 0) ? 128 : 64;
  constexpr int MF = (MODE == 0) ? 4 : 2;       // m-frags per wave
  __shared__ __align__(16) char smem[MODE == 0 ? 35840 : 12288];
  ushort* As = (ushort*)smem;                         // [BM][32]
  ushort* Bs = (ushort*)(smem + (MODE == 0 ? 8192 : 4096));  // [128][32]
  ushort* Tl = (ushort*)smem;            // V epilogue transpose [128][140]
  ushort* Tl2 = (ushort*)smem;           // Q/K epilogue stage [128][136]

  const int bm = blockIdx.x * BM;
  const int bn = blockIdx.y * 128;
  const int tid = threadIdx.x;
  const int wave = tid >> 6, lane = tid & 63;
  const int g = lane >> 4, ln = lane & 15;
  const int wr = wave >> 1, wc = wave & 1;

  f32x4 acc[MF][4];
#pragma unroll
  for (int m = 0; m < MF; ++m)
#pragma unroll
    for (int n = 0; n < 4; ++n) acc[m][n] = (f32x4){0.f, 0.f, 0.f, 0.f};

  const size_t a_base = (size_t)(bm + wave * 16 + (lane >> 2)) * INDIM + (lane & 3) * 8;
  const size_t b_base = (size_t)(bn + wave * 16 + (lane >> 2)) * INDIM + (lane & 3) * 8;
  ushort* ldsA0 = As + wave * 512;
  ushort* ldsA1 = As + 2048 + wave * 512;
  ushort* ldsB0 = Bs + wave * 512;
  ushort* ldsB1 = Bs + 2048 + wave * 512;

  for (int k0 = 0; k0 < INDIM; k0 += 32) {
    __syncthreads();
    __builtin_amdgcn_global_load_lds(
        (const __attribute__((address_space(1))) void*)(A + a_base + k0),
        (__attribute__((address_space(3))) void*)ldsA0, 16, 0, 0);
    if (MODE == 0)
      __builtin_amdgcn_global_load_lds(
          (const __attribute__((address_space(1))) void*)(A + a_base + 64 * INDIM + k0),
          (__attribute__((address_space(3))) void*)ldsA1, 16, 0, 0);
    __builtin_amdgcn_global_load_lds(
        (const __attribute__((address_space(1))) void*)(W + b_base + k0),
        (__attribute__((address_space(3))) void*)ldsB0, 16, 0, 0);
    __builtin_amdgcn_global_load_lds(
        (const __attribute__((address_space(1))) void*)(W + b_base + 64 * INDIM + k0),
        (__attribute__((address_space(3))) void*)ldsB1, 16, 0, 0);
    __syncthreads();

    bf16x8 af[MF], bfv[4];
#pragma unroll
    for (int m = 0; m < MF; ++m)
      af[m] = *(const bf16x8*)&As[((MODE == 0 ? 64 : 32) * wr + 16 * m + ln) * 32 + 8 * g];
#pragma unroll
    for (int n = 0; n < 4; ++n)
      bfv[n] = *(const bf16x8*)&Bs[(64 * wc + 16 * n + ln) * 32 + 8 * g];
#pragma unroll
    for (int m = 0; m < MF; ++m)
#pragma unroll
      for (int n = 0; n < 4; ++n)
        acc[m][n] = __builtin_amdgcn_mfma_f32_16x16x32_bf16(af[m], bfv[n], acc[m][n], 0, 0, 0);
  }

  // ---- epilogue ----
  if (MODE == 1) {
#pragma unroll
    for (int n = 0; n < 4; ++n) {
      const int e = bn + 64 * wc + 16 * n + ln;
      const float bv = b0[e];
#pragma unroll
      for (int m = 0; m < MF; ++m)
#pragma unroll
        for (int r = 0; r < 4; ++r) {
          const int row = bm + 32 * wr + 16 * m + 4 * g + r;
          outF[(size_t)row * EMB + e] = acc[m][n][r] + bv;
        }
    }
    return;
  }

  const int which = bn >> 9;
  const float* bias = (which == 0) ? b0 : (which == 1) ? b1 : b2;

  if (which < 2) {
    // Q gets the softmax scale folded in (log2 domain): 0.125 * log2(e)
    const float scl = (which == 0) ? 0.18033688f : 1.0f;
    ushort* dst = (which == 0) ? outQ : outK;
    __syncthreads();   // As/Bs reads done; reuse smem as Tl2[128][136]
#pragma unroll
    for (int n = 0; n < 4; ++n) {
      const int cl = 64 * wc + 16 * n + ln;
      const float bv = bias[(bn & 511) + cl];
#pragma unroll
      for (int m = 0; m < 4; ++m)
#pragma unroll
        for (int r = 0; r < 4; ++r) {
          const int rl = 64 * wr + 16 * m + 4 * g + r;
          Tl2[rl * 136 + cl] = f2bf((acc[m][n][r] + bv) * scl);
        }
    }
    __syncthreads();
    // coalesced write-out: 256 segments of 128B (row rl x head-half)
#pragma unroll
    for (int j = 0; j < 8; ++j) {
      const int cid = j * 256 + tid;      // 0..2047
      const int seg = cid >> 3;           // 0..255
      const int l8 = cid & 7;
      const int rl = seg >> 1, half = seg & 1;
      const int row = bm + rl;
      const int b = row >> 11, nn = row & (SEQ - 1);
      const int h = ((bn & 511) >> 6) + half;
      const bf16x8 v = *(const bf16x8*)&Tl2[rl * 136 + half * 64 + l8 * 8];
      *(bf16x8*)&dst[(((size_t)(b * NHEADS + h) * SEQ) + nn) * DH + l8 * 8] = v;
    }
  } else {
    // V: transpose through LDS, write V^T [B,H,Dh,N]
    __syncthreads();
#pragma unroll
    for (int n = 0; n < 4; ++n) {
      const int cl = 64 * wc + 16 * n + ln;
      const float bv = bias[(bn & 511) + cl];
#pragma unroll
      for (int m = 0; m < 4; ++m)
#pragma unroll
        for (int r = 0; r < 4; ++r) {
          const int rl = 64 * wr + 16 * m + 4 * g + r;
          Tl[cl * 140 + rl] = f2bf(acc[m][n][r] + bv);
        }
    }
    __syncthreads();
    const int c = tid >> 1;
    const int rh = (tid & 1) * 64;
    const int e = (bn & 511) + c;
    const int h = e >> 6, d = e & 63;
    const int b = bm >> 11;
    const int nn0 = (bm & (SEQ - 1)) + rh;
    ushort* drow = outVT + (((size_t)(b * NHEADS + h) * DH) + d) * SEQ + nn0;
#pragma unroll
    for (int j = 0; j < 8; ++j)
      *(bf16x8*)&drow[j * 8] = *(const bf16x8*)&Tl[c * 140 + rh + j * 8];
  }
}

// ---------------------------------------------------------------------------
// MFMA flash attention: IN-BLOCK kv-split x2 built from the R12-VERBATIM loop.
// 512 threads = 8 waves; half = tid>>8 processes kv in [half*1024, +1024)
// with the R12-verified body (kv-step 64, double-buffered per-half LDS,
// merged-phase A/B, 1 barrier/iter, 16 iters) on buffers Kl[half]/Vl[half].
// 512 blocks x 8 waves = 4096 waves = 4 waves/SIMD.
// LAUNCH BOUNDS FIX vs R17: (512,4) forced a 64-VGPR cap on a ~120-VGPR body
// -> 561MB of scratch spill writes, 202us. (512,2) allows the natural ~124
// VGPR (<=128), which still admits 4 waves/SIMD; LDS 73.7KB -> 2 blocks/CU.
// Combine: half 0 writes f32 acc + lane-local denominators to an LDS overlay
// (dead K/V space), barrier, half 1 adds its partials, normalizes, stores
// bf16 -- deterministic.
// Denominator via ones-MFMA, in-register P (pi-permuted K staging + cvt_pk +
// permlane32_swap), static-max exp2 softmax (Q pre-scaled by 0.125*log2e),
// XCD swizzle, bf16 O.
// ---------------------------------------------------------------------------
__global__ __launch_bounds__(512, 2) void attn_mfma(const ushort* __restrict__ Q,
                                                    const ushort* __restrict__ K,
                                                    const ushort* __restrict__ VT,
                                                    ushort* __restrict__ O) {
  __shared__ __align__(16) ushort Kl[2][2][64 * 72];  // [half][buf][kv(pi)][d]
  __shared__ __align__(16) ushort Vl[2][2][64 * 72];  // [half][buf][d][kv]

  const int tid = threadIdx.x;
  const int half = tid >> 8;            // kv half
  const int ltid = tid & 255;           // local tid within half
  const int wave = ltid >> 6, lane = ltid & 63;
  const int g = lane >> 4, ln = lane & 15;

  // XCD swizzle over 512 wgs: swz = (orig%8)*64 + orig/8 (bijective; 4 bh/XCD)
  const int orig = blockIdx.x;
  const int swz = (orig & 7) * 64 + (orig >> 3);
  const int bh = swz >> 4;            // 0..31
  const int qx = swz & 15;            // 0..15
  const int qbase = qx * 128 + wave * 32;
  const int kvbase = half << 10;      // 0 or 1024

  const ushort* Qb = Q + ((size_t)bh * SEQ + qbase) * DH;
  const ushort* Kb = K + (size_t)bh * SEQ * DH;
  const ushort* Vb = VT + (size_t)bh * DH * SEQ;

  const bf16x8 qfA0 = *(const bf16x8*)&Qb[ln * DH + 8 * g];
  const bf16x8 qfA1 = *(const bf16x8*)&Qb[ln * DH + 32 + 8 * g];
  const bf16x8 qfB0 = *(const bf16x8*)&Qb[(16 + ln) * DH + 8 * g];
  const bf16x8 qfB1 = *(const bf16x8*)&Qb[(16 + ln) * DH + 32 + 8 * g];

  // ones B-fragment for the denominator MFMA (bf16 1.0 = 0x3F80)
  bf16x8 vones;
#pragma unroll
  for (int i = 0; i < 8; ++i) vones[i] = (short)0x3F80;

  f32x4 oaccA[4], oaccB[4];
  f32x4 oaccDA = (f32x4){0.f, 0.f, 0.f, 0.f};
  f32x4 oaccDB = (f32x4){0.f, 0.f, 0.f, 0.f};
#pragma unroll
  for (int t = 0; t < 4; ++t) {
    oaccA[t] = (f32x4){0.f, 0.f, 0.f, 0.f};
    oaccB[t] = (f32x4){0.f, 0.f, 0.f, 0.f};
  }

  const int skv = ltid >> 3, sd = (ltid & 7) * 8;   // K staging (rows skv, skv+32)
  const int dt = ltid >> 2, kc = (ltid & 3) * 8;    // V staging
  // pi-permuted LDS rows for K: XOR 12 where bit2^bit3 (swaps rows 4-7 <-> 8-11)
  const int pr0 = skv ^ (((((skv >> 2) ^ (skv >> 3)) & 1)) * 12);
  const int s32 = skv + 32;
  const int pr1 = s32 ^ (((((s32 >> 2) ^ (s32 >> 3)) & 1)) * 12);

  // ---- preload: tile 0 -> regs -> buf0; tile 1 -> regs ----
  bf16x8 k0v = *(const bf16x8*)&Kb[(size_t)(kvbase + skv) * DH + sd];
  bf16x8 k1v = *(const bf16x8*)&Kb[(size_t)(kvbase + 32 + skv) * DH + sd];
  bf16x8 v0v = *(const bf16x8*)&Vb[(size_t)dt * SEQ + kvbase + kc];
  bf16x8 v1v = *(const bf16x8*)&Vb[(size_t)dt * SEQ + kvbase + 32 + kc];
  *(bf16x8*)&Kl[half][0][pr0 * 72 + sd] = k0v;
  *(bf16x8*)&Kl[half][0][pr1 * 72 + sd] = k1v;
  *(bf16x8*)&Vl[half][0][dt * 72 + kc] = v0v;
  *(bf16x8*)&Vl[half][0][dt * 72 + 32 + kc] = v1v;
  k0v = *(const bf16x8*)&Kb[(size_t)(kvbase + 64 + skv) * DH + sd];
  k1v = *(const bf16x8*)&Kb[(size_t)(kvbase + 96 + skv) * DH + sd];
  v0v = *(const bf16x8*)&Vb[(size_t)dt * SEQ + kvbase + 64 + kc];
  v1v = *(const bf16x8*)&Vb[(size_t)dt * SEQ + kvbase + 96 + kc];
  asm volatile("s_waitcnt lgkmcnt(0)" ::: "memory");
  __builtin_amdgcn_s_barrier();

  for (int it = 0; it < 16; ++it) {
    const int cur = it & 1;
    const ushort* Kc = Kl[half][cur];
    const ushort* Vc = Vl[half][cur];

    // stage tile it+1 into the other buffer (regs hold it+1)
    if (it < 15) {
      ushort* Kn = Kl[half][cur ^ 1];
      ushort* Vn = Vl[half][cur ^ 1];
      *(bf16x8*)&Kn[pr0 * 72 + sd] = k0v;
      *(bf16x8*)&Kn[pr1 * 72 + sd] = k1v;
      *(bf16x8*)&Vn[dt * 72 + kc] = v0v;
      *(bf16x8*)&Vn[dt * 72 + 32 + kc] = v1v;
    }
    // prefetch tile it+2 (clamped; redundant tail loads harmless)
    {
      const int nxt = kvbase + ((it + 2 < 16) ? (it + 2) * 64 : 15 * 64);
      k0v = *(const bf16x8*)&Kb[(size_t)(nxt + skv) * DH + sd];
      k1v = *(const bf16x8*)&Kb[(size_t)(nxt + 32 + skv) * DH + sd];
      v0v = *(const bf16x8*)&Vb[(size_t)dt * SEQ + nxt + kc];
      v1v = *(const bf16x8*)&Vb[(size_t)dt * SEQ + nxt + 32 + kc];
    }

    // ---- shared fragments, read ONCE, reused by both q-groups ----
    bf16x8 ka[4][2], vb[2][4];
#pragma unroll
    for (int t = 0; t < 4; ++t) {
      ka[t][0] = *(const bf16x8*)&Kc[(16 * t + ln) * 72 + 8 * g];
      ka[t][1] = *(const bf16x8*)&Kc[(16 * t + ln) * 72 + 32 + 8 * g];
    }
#pragma unroll
    for (int c = 0; c < 2; ++c)
#pragma unroll
      for (int t = 0; t < 4; ++t)
        vb[c][t] = *(const bf16x8*)&Vc[(16 * t + ln) * 72 + 32 * c + 8 * g];

    // ---- QK^T, BOTH groups in one batch (8 independent acc chains) ----
    f32x4 sA0 = (f32x4){0.f, 0.f, 0.f, 0.f};
    f32x4 sA1 = sA0, sA2 = sA0, sA3 = sA0;
    f32x4 sB0 = sA0, sB1 = sA0, sB2 = sA0, sB3 = sA0;
    __builtin_amdgcn_s_setprio(1);
    sA0 = __builtin_amdgcn_mfma_f32_16x16x32_bf16(ka[0][0], qfA0, sA0, 0, 0, 0);
    sB0 = __builtin_amdgcn_mfma_f32_16x16x32_bf16(ka[0][0], qfB0, sB0, 0, 0, 0);
    sA1 = __builtin_amdgcn_mfma_f32_16x16x32_bf16(ka[1][0], qfA0, sA1, 0, 0, 0);
    sB1 = __builtin_amdgcn_mfma_f32_16x16x32_bf16(ka[1][0], qfB0, sB1, 0, 0, 0);
    sA2 = __builtin_amdgcn_mfma_f32_16x16x32_bf16(ka[2][0], qfA0, sA2, 0, 0, 0);
    sB2 = __builtin_amdgcn_mfma_f32_16x16x32_bf16(ka[2][0], qfB0, sB2, 0, 0, 0);
    sA3 = __builtin_amdgcn_mfma_f32_16x16x32_bf16(ka[3][0], qfA0, sA3, 0, 0, 0);
    sB3 = __builtin_amdgcn_mfma_f32_16x16x32_bf16(ka[3][0], qfB0, sB3, 0, 0, 0);
    sA0 = __builtin_amdgcn_mfma_f32_16x16x32_bf16(ka[0][1], qfA1, sA0, 0, 0, 0);
    sB0 = __builtin_amdgcn_mfma_f32_16x16x32_bf16(ka[0][1], qfB1, sB0, 0, 0, 0);
    sA1 = __builtin_amdgcn_mfma_f32_16x16x32_bf16(ka[1][1], qfA1, sA1, 0, 0, 0);
    sB1 = __builtin_amdgcn_mfma_f32_16x16x32_bf16(ka[1][1], qfB1, sB1, 0, 0, 0);
    sA2 = __builtin_amdgcn_mfma_f32_16x16x32_bf16(ka[2][1], qfA1, sA2, 0, 0, 0);
    sB2 = __builtin_amdgcn_mfma_f32_16x16x32_bf16(ka[2][1], qfB1, sB2, 0, 0, 0);
    sA3 = __builtin_amdgcn_mfma_f32_16x16x32_bf16(ka[3][1], qfA1, sA3, 0, 0, 0);
    sB3 = __builtin_amdgcn_mfma_f32_16x16x32_bf16(ka[3][1], qfB1, sB3, 0, 0, 0);
    __builtin_amdgcn_s_setprio(0);

    // ---- P = exp2(S), BOTH groups (32 independent trans ops) ----
    float pA0[4], pA1[4], pA2[4], pA3[4];
    float pB0[4], pB1[4], pB2[4], pB3[4];
#pragma unroll
    for (int r = 0; r < 4; ++r) {
      pA0[r] = fast_exp2(sA0[r]);
      pA1[r] = fast_exp2(sA1[r]);
      pA2[r] = fast_exp2(sA2[r]);
      pA3[r] = fast_exp2(sA3[r]);
      pB0[r] = fast_exp2(sB0[r]);
      pB1[r] = fast_exp2(sB1[r]);
      pB2[r] = fast_exp2(sB2[r]);
      pB3[r] = fast_exp2(sB3[r]);
    }

    // ---- pack + permlane -> PV A-fragments, BOTH groups (no LDS) ----
    unsigned aa0 = cvt_pk_bf16(pA0[0], pA0[1]);
    unsigned aa2 = cvt_pk_bf16(pA1[0], pA1[1]);
    unsigned aa1 = cvt_pk_bf16(pA0[2], pA0[3]);
    unsigned aa3 = cvt_pk_bf16(pA1[2], pA1[3]);
    permswap32(aa0, aa2);
    permswap32(aa1, aa3);
    unsigned ab0 = cvt_pk_bf16(pA2[0], pA2[1]);
    unsigned ab2 = cvt_pk_bf16(pA3[0], pA3[1]);
    unsigned ab1 = cvt_pk_bf16(pA2[2], pA2[3]);
    unsigned ab3 = cvt_pk_bf16(pA3[2], pA3[3]);
    permswap32(ab0, ab2);
    permswap32(ab1, ab3);
    unsigned ba0 = cvt_pk_bf16(pB0[0], pB0[1]);
    unsigned ba2 = cvt_pk_bf16(pB1[0], pB1[1]);
    unsigned ba1 = cvt_pk_bf16(pB0[2], pB0[3]);
    unsigned ba3 = cvt_pk_bf16(pB1[2], pB1[3]);
    permswap32(ba0, ba2);
    permswap32(ba1, ba3);
    unsigned bb0 = cvt_pk_bf16(pB2[0], pB2[1]);
    unsigned bb2 = cvt_pk_bf16(pB3[0], pB3[1]);
    unsigned bb1 = cvt_pk_bf16(pB2[2], pB2[3]);
    unsigned bb3 = cvt_pk_bf16(pB3[2], pB3[3]);
    permswap32(bb0, bb2);
    permswap32(bb1, bb3);
    union { unsigned u[4]; bf16x8 v; } paA0, paA1, paB0, paB1;
    paA0.u[0] = aa0; paA0.u[1] = aa1; paA0.u[2] = aa2; paA0.u[3] = aa3;
    paA1.u[0] = ab0; paA1.u[1] = ab1; paA1.u[2] = ab2; paA1.u[3] = ab3;
    paB0.u[0] = ba0; paB0.u[1] = ba1; paB0.u[2] = ba2; paB0.u[3] = ba3;
    paB1.u[0] = bb0; paB1.u[1] = bb1; paB1.u[2] = bb2; paB1.u[3] = bb3;

    // ---- PV + denominators, BOTH groups in one MFMA batch ----
    __builtin_amdgcn_s_setprio(1);
#pragma unroll
    for (int t = 0; t < 4; ++t) {
      oaccA[t] = __builtin_amdgcn_mfma_f32_16x16x32_bf16(paA0.v, vb[0][t], oaccA[t], 0, 0, 0);
      oaccB[t] = __builtin_amdgcn_mfma_f32_16x16x32_bf16(paB0.v, vb[0][t], oaccB[t], 0, 0, 0);
      oaccA[t] = __builtin_amdgcn_mfma_f32_16x16x32_bf16(paA1.v, vb[1][t], oaccA[t], 0, 0, 0);
      oaccB[t] = __builtin_amdgcn_mfma_f32_16x16x32_bf16(paB1.v, vb[1][t], oaccB[t], 0, 0, 0);
    }
    oaccDA = __builtin_amdgcn_mfma_f32_16x16x32_bf16(paA0.v, vones, oaccDA, 0, 0, 0);
    oaccDB = __builtin_amdgcn_mfma_f32_16x16x32_bf16(paB0.v, vones, oaccDB, 0, 0, 0);
    oaccDA = __builtin_amdgcn_mfma_f32_16x16x32_bf16(paA1.v, vones, oaccDA, 0, 0, 0);
    oaccDB = __builtin_amdgcn_mfma_f32_16x16x32_bf16(paB1.v, vones, oaccDB, 0, 0, 0);
    __builtin_amdgcn_s_setprio(0);

    // single barrier per iter: my ds reads (buf cur) + writes (buf cur^1) done
    asm volatile("s_waitcnt lgkmcnt(0)" ::: "memory");
    __builtin_amdgcn_s_barrier();
  }

  // ---- combine halves through LDS overlay (K/V buffers are dead) ----
  float* Acc = (float*)&Kl[0][0][0];    // [128][68] f32 = 34816B (fits 36864B)
  float* Dl  = (float*)&Vl[0][0][0];    // [128] f32
  __syncthreads();
  if (half == 0) {
#pragma unroll
    for (int t = 0; t < 4; ++t)
#pragma unroll
      for (int r = 0; r < 4; ++r) {
        Acc[(wave * 32 + 4 * g + r) * 68 + 16 * t + ln] = oaccA[t][r];
        Acc[(wave * 32 + 16 + 4 * g + r) * 68 + 16 * t + ln] = oaccB[t][r];
      }
    if (ln == 0) {
#pragma unroll
      for (int r = 0; r < 4; ++r) {
        Dl[wave * 32 + 4 * g + r] = oaccDA[r];
        Dl[wave * 32 + 16 + 4 * g + r] = oaccDB[r];
      }
    }
  }
  __syncthreads();
  if (half == 1) {
    const int b = bh >> 3, h = bh & 7;
#pragma unroll
    for (int r = 0; r < 4; ++r) {
      const int rowA = wave * 32 + 4 * g + r;
      const int rowB = rowA + 16;
      const float irA = 1.0f / (Dl[rowA] + oaccDA[r]);
      const float irB = 1.0f / (Dl[rowB] + oaccDB[r]);
      ushort* opA = O + ((size_t)(b * SEQ) + qx * 128 + rowA) * EMB + h * 64;
      ushort* opB = O + ((size_t)(b * SEQ) + qx * 128 + rowB) * EMB + h * 64;
#pragma unroll
      for (int t = 0; t < 4; ++t) {
        opA[16 * t + ln] = f2bf((Acc[rowA * 68 + 16 * t + ln] + oaccA[t][r]) * irA);
        opB[16 * t + ln] = f2bf((Acc[rowB * 68 + 16 * t + ln] + oaccB[t][r]) * irB);
      }
    }
  }
}

// ---------------------------------------------------------------------------
extern "C" void kernel_launch(void* const* d_in, const int* in_sizes, int n_in,
                              void* d_out, int out_size, void* d_ws, size_t ws_size,
                              hipStream_t stream) {
  const float* q  = (const float*)d_in[0];
  const float* wq = (const float*)d_in[1];
  const float* bq = (const float*)d_in[2];
  const float* wk = (const float*)d_in[3];
  const float* bk = (const float*)d_in[4];
  const float* wv = (const float*)d_in[5];
  const float* bv = (const float*)d_in[6];
  const float* wo = (const float*)d_in[7];
  const float* bo = (const float*)d_in[8];
  float* out = (float*)d_out;

  const size_t XSZ = (size_t)MTOT * INDIM;
  const size_t WSZ = (size_t)EMB * INDIM;
  const size_t QSZ = (size_t)BATCH * NHEADS * SEQ * DH;
  ushort* wsX = (ushort*)d_ws;
  ushort* wsW = wsX + XSZ;
  ushort* wsQ = wsW + 4 * WSZ;
  ushort* wsK = wsQ + QSZ;
  ushort* wsVT = wsK + QSZ;
  ushort* wsA = wsVT + QSZ;   // attn output bf16 [B,N,EMB]

  const dim3 blk(256);

  conv_bf16<<<dim3(XSZ / 8 / 256), blk, 0, stream>>>(q, wsX, XSZ / 8);
  conv_bf16_w4<<<dim3(WSZ / 8 / 256, 4), blk, 0, stream>>>(wq, wk, wv, wo, wsW, WSZ / 8);

  mfma_gemm<0><<<dim3(MTOT / 128, 1536 / 128), blk, 0, stream>>>(
      wsX, wsW, bq, bk, bv, wsQ, wsK, wsVT, nullptr);

  attn_mfma<<<dim3(512), dim3(512), 0, stream>>>(wsQ, wsK, wsVT, wsA);

  mfma_gemm<1><<<dim3(MTOT / 64, EMB / 128), blk, 0, stream>>>(
      wsA, wsW + 3 * WSZ, bo, nullptr, nullptr, nullptr, nullptr, nullptr, out);
}

// Round 19
// 96.175 us; speedup vs baseline: 2.5720x; 1.0327x over previous
//
#include <hip/hip_runtime.h>
#include <hip/hip_bf16.h>
#include <math.h>

#define SEQ    2048
#define DH     64
#define EMB    512
#define INDIM  512
#define NHEADS 8
#define BATCH  4
#define MTOT   (BATCH * SEQ)   // 8192

typedef __attribute__((ext_vector_type(8))) short bf16x8;   // 8 bf16 = 4 VGPR
typedef __attribute__((ext_vector_type(4))) float f32x4;

__device__ __forceinline__ ushort f2bf(float x) {
  union { float f; unsigned u; } v; v.f = x;
  unsigned r = v.u + 0x7FFFu + ((v.u >> 16) & 1u);   // RNE
  return (ushort)(r >> 16);
}

// packed f32x2 -> bf16x2 (single HW op)
__device__ __forceinline__ unsigned cvt_pk_bf16(float lo, float hi) {
  unsigned r;
  asm("v_cvt_pk_bf16_f32 %0, %1, %2" : "=v"(r) : "v"(lo), "v"(hi));
  return r;
}

// raw v_exp_f32 (exp2); args bounded (static-max softmax)
__device__ __forceinline__ float fast_exp2(float x) {
  float r;
  asm("v_exp_f32 %0, %1" : "=v"(r) : "v"(x));
  return r;
}

// v_permlane32_swap_b32: after: x = [x.h0, y.h0], y = [x.h1, y.h1] (lane halves)
__device__ __forceinline__ void permswap32(unsigned &x, unsigned &y) {
  asm("v_permlane32_swap_b32 %0, %1" : "+v"(x), "+v"(y));
}

// ---------------------------------------------------------------------------
// Fused f32 -> bf16 conversion for X + the 4 weight matrices, ONE launch.
// Flat uint4 index space: [0, nX) -> X; [nX, nX + 4*nW) -> weights.
// ---------------------------------------------------------------------------
__global__ __launch_bounds__(256) void conv_all(
    const float* __restrict__ x, const float* __restrict__ w0,
    const float* __restrict__ w1, const float* __restrict__ w2,
    const float* __restrict__ w3,
    ushort* __restrict__ dstX, ushort* __restrict__ dstW,
    int nX, int nW) {
  const int i = blockIdx.x * 256 + threadIdx.x;
  const float* src;
  ushort* dst;
  int idx;
  if (i < nX) {
    src = x; dst = dstX; idx = i;
  } else {
    const int j = i - nX;
    const int w = j / nW;        // 0..3 (uniform per block: nW = 32768 = 128 blocks)
    idx = j - w * nW;
    src = (w == 0) ? w0 : (w == 1) ? w1 : (w == 2) ? w2 : w3;
    dst = dstW + (size_t)w * nW * 8;
  }
  const float4 a = ((const float4*)src)[idx * 2];
  const float4 b = ((const float4*)src)[idx * 2 + 1];
  uint4 o;
  o.x = cvt_pk_bf16(a.x, a.y);
  o.y = cvt_pk_bf16(a.z, a.w);
  o.z = cvt_pk_bf16(b.x, b.y);
  o.w = cvt_pk_bf16(b.z, b.w);
  ((uint4*)dst)[idx] = o;
}

// ---------------------------------------------------------------------------
// MFMA GEMM, m97 structure, BK=32, 4 waves, global_load_lds width 16.
// MODE 0: 128x128 tile. Fused QKV (N=1536). which=bn>>9: 0->Q (pre-scaled
//         by 0.125*log2e), 1->K bf16 [B,H,N,Dh] (coalesced via LDS re-stage);
//         2->V^T bf16 [B,H,Dh,N] via LDS transpose.
// MODE 1: 64x128 tile (grid 512 = 2 blocks/CU). f32 out [M][EMB]+bias.
// ---------------------------------------------------------------------------
template <int MODE>
__global__ __launch_bounds__(256) void mfma_gemm(
    const ushort* __restrict__ A, const ushort* __restrict__ W,
    const float* __restrict__ b0, const float* __restrict__ b1,
    const float* __restrict__ b2,
    ushort* __restrict__ outQ, ushort* __restrict__ outK,
    ushort* __restrict__ outVT, float* __restrict__ outF) {
  constexpr int BM = (MODE == 0) ? 128 : 64;
  constexpr int MF = (MODE == 0) ? 4 : 2;       // m-frags per wave
  __shared__ __align__(16) char smem[MODE == 0 ? 35840 : 12288];
  ushort* As = (ushort*)smem;                         // [BM][32]
  ushort* Bs = (ushort*)(smem + (MODE == 0 ? 8192 : 4096));  // [128][32]
  ushort* Tl = (ushort*)smem;            // V epilogue transpose [128][140]
  ushort* Tl2 = (ushort*)smem;           // Q/K epilogue stage [128][136]

  const int bm = blockIdx.x * BM;
  const int bn = blockIdx.y * 128;
  const int tid = threadIdx.x;
  const int wave = tid >> 6, lane = tid & 63;
  const int g = lane >> 4, ln = lane & 15;
  const int wr = wave >> 1, wc = wave & 1;

  f32x4 acc[MF][4];
#pragma unroll
  for (int m = 0; m < MF; ++m)
#pragma unroll
    for (int n = 0; n < 4; ++n) acc[m][n] = (f32x4){0.f, 0.f, 0.f, 0.f};

  const size_t a_base = (size_t)(bm + wave * 16 + (lane >> 2)) * INDIM + (lane & 3) * 8;
  const size_t b_base = (size_t)(bn + wave * 16 + (lane >> 2)) * INDIM + (lane & 3) * 8;
  ushort* ldsA0 = As + wave * 512;
  ushort* ldsA1 = As + 2048 + wave * 512;
  ushort* ldsB0 = Bs + wave * 512;
  ushort* ldsB1 = Bs + 2048 + wave * 512;

  for (int k0 = 0; k0 < INDIM; k0 += 32) {
    __syncthreads();
    __builtin_amdgcn_global_load_lds(
        (const __attribute__((address_space(1))) void*)(A + a_base + k0),
        (__attribute__((address_space(3))) void*)ldsA0, 16, 0, 0);
    if (MODE == 0)
      __builtin_amdgcn_global_load_lds(
          (const __attribute__((address_space(1))) void*)(A + a_base + 64 * INDIM + k0),
          (__attribute__((address_space(3))) void*)ldsA1, 16, 0, 0);
    __builtin_amdgcn_global_load_lds(
        (const __attribute__((address_space(1))) void*)(W + b_base + k0),
        (__attribute__((address_space(3))) void*)ldsB0, 16, 0, 0);
    __builtin_amdgcn_global_load_lds(
        (const __attribute__((address_space(1))) void*)(W + b_base + 64 * INDIM + k0),
        (__attribute__((address_space(3))) void*)ldsB1, 16, 0, 0);
    __syncthreads();

    bf16x8 af[MF], bfv[4];
#pragma unroll
    for (int m = 0; m < MF; ++m)
      af[m] = *(const bf16x8*)&As[((MODE == 0 ? 64 : 32) * wr + 16 * m + ln) * 32 + 8 * g];
#pragma unroll
    for (int n = 0; n < 4; ++n)
      bfv[n] = *(const bf16x8*)&Bs[(64 * wc + 16 * n + ln) * 32 + 8 * g];
#pragma unroll
    for (int m = 0; m < MF; ++m)
#pragma unroll
      for (int n = 0; n < 4; ++n)
        acc[m][n] = __builtin_amdgcn_mfma_f32_16x16x32_bf16(af[m], bfv[n], acc[m][n], 0, 0, 0);
  }

  // ---- epilogue ----
  if (MODE == 1) {
#pragma unroll
    for (int n = 0; n < 4; ++n) {
      const int e = bn + 64 * wc + 16 * n + ln;
      const float bv = b0[e];
#pragma unroll
      for (int m = 0; m < MF; ++m)
#pragma unroll
        for (int r = 0; r < 4; ++r) {
          const int row = bm + 32 * wr + 16 * m + 4 * g + r;
          outF[(size_t)row * EMB + e] = acc[m][n][r] + bv;
        }
    }
    return;
  }

  const int which = bn >> 9;
  const float* bias = (which == 0) ? b0 : (which == 1) ? b1 : b2;

  if (which < 2) {
    // Q gets the softmax scale folded in (log2 domain): 0.125 * log2(e)
    const float scl = (which == 0) ? 0.18033688f : 1.0f;
    ushort* dst = (which == 0) ? outQ : outK;
    __syncthreads();   // As/Bs reads done; reuse smem as Tl2[128][136]
#pragma unroll
    for (int n = 0; n < 4; ++n) {
      const int cl = 64 * wc + 16 * n + ln;
      const float bv = bias[(bn & 511) + cl];
#pragma unroll
      for (int m = 0; m < 4; ++m)
#pragma unroll
        for (int r = 0; r < 4; ++r) {
          const int rl = 64 * wr + 16 * m + 4 * g + r;
          Tl2[rl * 136 + cl] = f2bf((acc[m][n][r] + bv) * scl);
        }
    }
    __syncthreads();
    // coalesced write-out: 256 segments of 128B (row rl x head-half)
#pragma unroll
    for (int j = 0; j < 8; ++j) {
      const int cid = j * 256 + tid;      // 0..2047
      const int seg = cid >> 3;           // 0..255
      const int l8 = cid & 7;
      const int rl = seg >> 1, half = seg & 1;
      const int row = bm + rl;
      const int b = row >> 11, nn = row & (SEQ - 1);
      const int h = ((bn & 511) >> 6) + half;
      const bf16x8 v = *(const bf16x8*)&Tl2[rl * 136 + half * 64 + l8 * 8];
      *(bf16x8*)&dst[(((size_t)(b * NHEADS + h) * SEQ) + nn) * DH + l8 * 8] = v;
    }
  } else {
    // V: transpose through LDS, write V^T [B,H,Dh,N]
    __syncthreads();
#pragma unroll
    for (int n = 0; n < 4; ++n) {
      const int cl = 64 * wc + 16 * n + ln;
      const float bv = bias[(bn & 511) + cl];
#pragma unroll
      for (int m = 0; m < 4; ++m)
#pragma unroll
        for (int r = 0; r < 4; ++r) {
          const int rl = 64 * wr + 16 * m + 4 * g + r;
          Tl[cl * 140 + rl] = f2bf(acc[m][n][r] + bv);
        }
    }
    __syncthreads();
    const int c = tid >> 1;
    const int rh = (tid & 1) * 64;
    const int e = (bn & 511) + c;
    const int h = e >> 6, d = e & 63;
    const int b = bm >> 11;
    const int nn0 = (bm & (SEQ - 1)) + rh;
    ushort* drow = outVT + (((size_t)(b * NHEADS + h) * DH) + d) * SEQ + nn0;
#pragma unroll
    for (int j = 0; j < 8; ++j)
      *(bf16x8*)&drow[j * 8] = *(const bf16x8*)&Tl[c * 140 + rh + j * 8];
  }
}

// ---------------------------------------------------------------------------
// MFMA flash attention: IN-BLOCK kv-split x2 built from the R12-verified loop.
// 512 threads = 8 waves; half = tid>>8 processes kv in [half*1024, +1024)
// (kv-step 64, double-buffered per-half LDS, merged-phase A/B, 1 barrier/iter,
// 16 iters) on buffers Kl[half]/Vl[half]. launch_bounds (512,2): natural ~92
// VGPR, no spill (R17's (512,4) forced 64-VGPR cap -> 561MB scratch).
// Combine: half 0 writes f32 acc + lane-local denominators to an LDS overlay
// (dead K/V space), barrier, half 1 adds its partials, normalizes, stores
// bf16 -- deterministic.
// Denominator via ones-MFMA, in-register P (pi-permuted K staging + cvt_pk +
// permlane32_swap), static-max exp2 softmax (Q pre-scaled by 0.125*log2e),
// XCD swizzle, bf16 O.
// ---------------------------------------------------------------------------
__global__ __launch_bounds__(512, 2) void attn_mfma(const ushort* __restrict__ Q,
                                                    const ushort* __restrict__ K,
                                                    const ushort* __restrict__ VT,
                                                    ushort* __restrict__ O) {
  __shared__ __align__(16) ushort Kl[2][2][64 * 72];  // [half][buf][kv(pi)][d]
  __shared__ __align__(16) ushort Vl[2][2][64 * 72];  // [half][buf][d][kv]

  const int tid = threadIdx.x;
  const int half = tid >> 8;            // kv half
  const int ltid = tid & 255;           // local tid within half
  const int wave = ltid >> 6, lane = ltid & 63;
  const int g = lane >> 4, ln = lane & 15;

  // XCD swizzle over 512 wgs: swz = (orig%8)*64 + orig/8 (bijective; 4 bh/XCD)
  const int orig = blockIdx.x;
  const int swz = (orig & 7) * 64 + (orig >> 3);
  const int bh = swz >> 4;            // 0..31
  const int qx = swz & 15;            // 0..15
  const int qbase = qx * 128 + wave * 32;
  const int kvbase = half << 10;      // 0 or 1024

  const ushort* Qb = Q + ((size_t)bh * SEQ + qbase) * DH;
  const ushort* Kb = K + (size_t)bh * SEQ * DH;
  const ushort* Vb = VT + (size_t)bh * DH * SEQ;

  const bf16x8 qfA0 = *(const bf16x8*)&Qb[ln * DH + 8 * g];
  const bf16x8 qfA1 = *(const bf16x8*)&Qb[ln * DH + 32 + 8 * g];
  const bf16x8 qfB0 = *(const bf16x8*)&Qb[(16 + ln) * DH + 8 * g];
  const bf16x8 qfB1 = *(const bf16x8*)&Qb[(16 + ln) * DH + 32 + 8 * g];

  // ones B-fragment for the denominator MFMA (bf16 1.0 = 0x3F80)
  bf16x8 vones;
#pragma unroll
  for (int i = 0; i < 8; ++i) vones[i] = (short)0x3F80;

  f32x4 oaccA[4], oaccB[4];
  f32x4 oaccDA = (f32x4){0.f, 0.f, 0.f, 0.f};
  f32x4 oaccDB = (f32x4){0.f, 0.f, 0.f, 0.f};
#pragma unroll
  for (int t = 0; t < 4; ++t) {
    oaccA[t] = (f32x4){0.f, 0.f, 0.f, 0.f};
    oaccB[t] = (f32x4){0.f, 0.f, 0.f, 0.f};
  }

  const int skv = ltid >> 3, sd = (ltid & 7) * 8;   // K staging (rows skv, skv+32)
  const int dt = ltid >> 2, kc = (ltid & 3) * 8;    // V staging
  // pi-permuted LDS rows for K: XOR 12 where bit2^bit3 (swaps rows 4-7 <-> 8-11)
  const int pr0 = skv ^ (((((skv >> 2) ^ (skv >> 3)) & 1)) * 12);
  const int s32 = skv + 32;
  const int pr1 = s32 ^ (((((s32 >> 2) ^ (s32 >> 3)) & 1)) * 12);

  // ---- preload: tile 0 -> regs -> buf0; tile 1 -> regs ----
  bf16x8 k0v = *(const bf16x8*)&Kb[(size_t)(kvbase + skv) * DH + sd];
  bf16x8 k1v = *(const bf16x8*)&Kb[(size_t)(kvbase + 32 + skv) * DH + sd];
  bf16x8 v0v = *(const bf16x8*)&Vb[(size_t)dt * SEQ + kvbase + kc];
  bf16x8 v1v = *(const bf16x8*)&Vb[(size_t)dt * SEQ + kvbase + 32 + kc];
  *(bf16x8*)&Kl[half][0][pr0 * 72 + sd] = k0v;
  *(bf16x8*)&Kl[half][0][pr1 * 72 + sd] = k1v;
  *(bf16x8*)&Vl[half][0][dt * 72 + kc] = v0v;
  *(bf16x8*)&Vl[half][0][dt * 72 + 32 + kc] = v1v;
  k0v = *(const bf16x8*)&Kb[(size_t)(kvbase + 64 + skv) * DH + sd];
  k1v = *(const bf16x8*)&Kb[(size_t)(kvbase + 96 + skv) * DH + sd];
  v0v = *(const bf16x8*)&Vb[(size_t)dt * SEQ + kvbase + 64 + kc];
  v1v = *(const bf16x8*)&Vb[(size_t)dt * SEQ + kvbase + 96 + kc];
  asm volatile("s_waitcnt lgkmcnt(0)" ::: "memory");
  __builtin_amdgcn_s_barrier();

  for (int it = 0; it < 16; ++it) {
    const int cur = it & 1;
    const ushort* Kc = Kl[half][cur];
    const ushort* Vc = Vl[half][cur];

    // stage tile it+1 into the other buffer (regs hold it+1)
    if (it < 15) {
      ushort* Kn = Kl[half][cur ^ 1];
      ushort* Vn = Vl[half][cur ^ 1];
      *(bf16x8*)&Kn[pr0 * 72 + sd] = k0v;
      *(bf16x8*)&Kn[pr1 * 72 + sd] = k1v;
      *(bf16x8*)&Vn[dt * 72 + kc] = v0v;
      *(bf16x8*)&Vn[dt * 72 + 32 + kc] = v1v;
    }
    // prefetch tile it+2 (clamped; redundant tail loads harmless)
    {
      const int nxt = kvbase + ((it + 2 < 16) ? (it + 2) * 64 : 15 * 64);
      k0v = *(const bf16x8*)&Kb[(size_t)(nxt + skv) * DH + sd];
      k1v = *(const bf16x8*)&Kb[(size_t)(nxt + 32 + skv) * DH + sd];
      v0v = *(const bf16x8*)&Vb[(size_t)dt * SEQ + nxt + kc];
      v1v = *(const bf16x8*)&Vb[(size_t)dt * SEQ + nxt + 32 + kc];
    }

    // ---- shared fragments, read ONCE, reused by both q-groups ----
    bf16x8 ka[4][2], vb[2][4];
#pragma unroll
    for (int t = 0; t < 4; ++t) {
      ka[t][0] = *(const bf16x8*)&Kc[(16 * t + ln) * 72 + 8 * g];
      ka[t][1] = *(const bf16x8*)&Kc[(16 * t + ln) * 72 + 32 + 8 * g];
    }
#pragma unroll
    for (int c = 0; c < 2; ++c)
#pragma unroll
      for (int t = 0; t < 4; ++t)
        vb[c][t] = *(const bf16x8*)&Vc[(16 * t + ln) * 72 + 32 * c + 8 * g];

    // ---- QK^T, BOTH groups in one batch (8 independent acc chains) ----
    f32x4 sA0 = (f32x4){0.f, 0.f, 0.f, 0.f};
    f32x4 sA1 = sA0, sA2 = sA0, sA3 = sA0;
    f32x4 sB0 = sA0, sB1 = sA0, sB2 = sA0, sB3 = sA0;
    __builtin_amdgcn_s_setprio(1);
    sA0 = __builtin_amdgcn_mfma_f32_16x16x32_bf16(ka[0][0], qfA0, sA0, 0, 0, 0);
    sB0 = __builtin_amdgcn_mfma_f32_16x16x32_bf16(ka[0][0], qfB0, sB0, 0, 0, 0);
    sA1 = __builtin_amdgcn_mfma_f32_16x16x32_bf16(ka[1][0], qfA0, sA1, 0, 0, 0);
    sB1 = __builtin_amdgcn_mfma_f32_16x16x32_bf16(ka[1][0], qfB0, sB1, 0, 0, 0);
    sA2 = __builtin_amdgcn_mfma_f32_16x16x32_bf16(ka[2][0], qfA0, sA2, 0, 0, 0);
    sB2 = __builtin_amdgcn_mfma_f32_16x16x32_bf16(ka[2][0], qfB0, sB2, 0, 0, 0);
    sA3 = __builtin_amdgcn_mfma_f32_16x16x32_bf16(ka[3][0], qfA0, sA3, 0, 0, 0);
    sB3 = __builtin_amdgcn_mfma_f32_16x16x32_bf16(ka[3][0], qfB0, sB3, 0, 0, 0);
    sA0 = __builtin_amdgcn_mfma_f32_16x16x32_bf16(ka[0][1], qfA1, sA0, 0, 0, 0);
    sB0 = __builtin_amdgcn_mfma_f32_16x16x32_bf16(ka[0][1], qfB1, sB0, 0, 0, 0);
    sA1 = __builtin_amdgcn_mfma_f32_16x16x32_bf16(ka[1][1], qfA1, sA1, 0, 0, 0);
    sB1 = __builtin_amdgcn_mfma_f32_16x16x32_bf16(ka[1][1], qfB1, sB1, 0, 0, 0);
    sA2 = __builtin_amdgcn_mfma_f32_16x16x32_bf16(ka[2][1], qfA1, sA2, 0, 0, 0);
    sB2 = __builtin_amdgcn_mfma_f32_16x16x32_bf16(ka[2][1], qfB1, sB2, 0, 0, 0);
    sA3 = __builtin_amdgcn_mfma_f32_16x16x32_bf16(ka[3][1], qfA1, sA3, 0, 0, 0);
    sB3 = __builtin_amdgcn_mfma_f32_16x16x32_bf16(ka[3][1], qfB1, sB3, 0, 0, 0);
    __builtin_amdgcn_s_setprio(0);

    // ---- P = exp2(S), BOTH groups (32 independent trans ops) ----
    float pA0[4], pA1[4], pA2[4], pA3[4];
    float pB0[4], pB1[4], pB2[4], pB3[4];
#pragma unroll
    for (int r = 0; r < 4; ++r) {
      pA0[r] = fast_exp2(sA0[r]);
      pA1[r] = fast_exp2(sA1[r]);
      pA2[r] = fast_exp2(sA2[r]);
      pA3[r] = fast_exp2(sA3[r]);
      pB0[r] = fast_exp2(sB0[r]);
      pB1[r] = fast_exp2(sB1[r]);
      pB2[r] = fast_exp2(sB2[r]);
      pB3[r] = fast_exp2(sB3[r]);
    }

    // ---- pack + permlane -> PV A-fragments, BOTH groups (no LDS) ----
    unsigned aa0 = cvt_pk_bf16(pA0[0], pA0[1]);
    unsigned aa2 = cvt_pk_bf16(pA1[0], pA1[1]);
    unsigned aa1 = cvt_pk_bf16(pA0[2], pA0[3]);
    unsigned aa3 = cvt_pk_bf16(pA1[2], pA1[3]);
    permswap32(aa0, aa2);
    permswap32(aa1, aa3);
    unsigned ab0 = cvt_pk_bf16(pA2[0], pA2[1]);
    unsigned ab2 = cvt_pk_bf16(pA3[0], pA3[1]);
    unsigned ab1 = cvt_pk_bf16(pA2[2], pA2[3]);
    unsigned ab3 = cvt_pk_bf16(pA3[2], pA3[3]);
    permswap32(ab0, ab2);
    permswap32(ab1, ab3);
    unsigned ba0 = cvt_pk_bf16(pB0[0], pB0[1]);
    unsigned ba2 = cvt_pk_bf16(pB1[0], pB1[1]);
    unsigned ba1 = cvt_pk_bf16(pB0[2], pB0[3]);
    unsigned ba3 = cvt_pk_bf16(pB1[2], pB1[3]);
    permswap32(ba0, ba2);
    permswap32(ba1, ba3);
    unsigned bb0 = cvt_pk_bf16(pB2[0], pB2[1]);
    unsigned bb2 = cvt_pk_bf16(pB3[0], pB3[1]);
    unsigned bb1 = cvt_pk_bf16(pB2[2], pB2[3]);
    unsigned bb3 = cvt_pk_bf16(pB3[2], pB3[3]);
    permswap32(bb0, bb2);
    permswap32(bb1, bb3);
    union { unsigned u[4]; bf16x8 v; } paA0, paA1, paB0, paB1;
    paA0.u[0] = aa0; paA0.u[1] = aa1; paA0.u[2] = aa2; paA0.u[3] = aa3;
    paA1.u[0] = ab0; paA1.u[1] = ab1; paA1.u[2] = ab2; paA1.u[3] = ab3;
    paB0.u[0] = ba0; paB0.u[1] = ba1; paB0.u[2] = ba2; paB0.u[3] = ba3;
    paB1.u[0] = bb0; paB1.u[1] = bb1; paB1.u[2] = bb2; paB1.u[3] = bb3;

    // ---- PV + denominators, BOTH groups in one MFMA batch ----
    __builtin_amdgcn_s_setprio(1);
#pragma unroll
    for (int t = 0; t < 4; ++t) {
      oaccA[t] = __builtin_amdgcn_mfma_f32_16x16x32_bf16(paA0.v, vb[0][t], oaccA[t], 0, 0, 0);
      oaccB[t] = __builtin_amdgcn_mfma_f32_16x16x32_bf16(paB0.v, vb[0][t], oaccB[t], 0, 0, 0);
      oaccA[t] = __builtin_amdgcn_mfma_f32_16x16x32_bf16(paA1.v, vb[1][t], oaccA[t], 0, 0, 0);
      oaccB[t] = __builtin_amdgcn_mfma_f32_16x16x32_bf16(paB1.v, vb[1][t], oaccB[t], 0, 0, 0);
    }
    oaccDA = __builtin_amdgcn_mfma_f32_16x16x32_bf16(paA0.v, vones, oaccDA, 0, 0, 0);
    oaccDB = __builtin_amdgcn_mfma_f32_16x16x32_bf16(paB0.v, vones, oaccDB, 0, 0, 0);
    oaccDA = __builtin_amdgcn_mfma_f32_16x16x32_bf16(paA1.v, vones, oaccDA, 0, 0, 0);
    oaccDB = __builtin_amdgcn_mfma_f32_16x16x32_bf16(paB1.v, vones, oaccDB, 0, 0, 0);
    __builtin_amdgcn_s_setprio(0);

    // single barrier per iter: my ds reads (buf cur) + writes (buf cur^1) done
    asm volatile("s_waitcnt lgkmcnt(0)" ::: "memory");
    __builtin_amdgcn_s_barrier();
  }

  // ---- combine halves through LDS overlay (K/V buffers are dead) ----
  float* Acc = (float*)&Kl[0][0][0];    // [128][68] f32 = 34816B (fits 36864B)
  float* Dl  = (float*)&Vl[0][0][0];    // [128] f32
  __syncthreads();
  if (half == 0) {
#pragma unroll
    for (int t = 0; t < 4; ++t)
#pragma unroll
      for (int r = 0; r < 4; ++r) {
        Acc[(wave * 32 + 4 * g + r) * 68 + 16 * t + ln] = oaccA[t][r];
        Acc[(wave * 32 + 16 + 4 * g + r) * 68 + 16 * t + ln] = oaccB[t][r];
      }
    if (ln == 0) {
#pragma unroll
      for (int r = 0; r < 4; ++r) {
        Dl[wave * 32 + 4 * g + r] = oaccDA[r];
        Dl[wave * 32 + 16 + 4 * g + r] = oaccDB[r];
      }
    }
  }
  __syncthreads();
  if (half == 1) {
    const int b = bh >> 3, h = bh & 7;
#pragma unroll
    for (int r = 0; r < 4; ++r) {
      const int rowA = wave * 32 + 4 * g + r;
      const int rowB = rowA + 16;
      const float irA = 1.0f / (Dl[rowA] + oaccDA[r]);
      const float irB = 1.0f / (Dl[rowB] + oaccDB[r]);
      ushort* opA = O + ((size_t)(b * SEQ) + qx * 128 + rowA) * EMB + h * 64;
      ushort* opB = O + ((size_t)(b * SEQ) + qx * 128 + rowB) * EMB + h * 64;
#pragma unroll
      for (int t = 0; t < 4; ++t) {
        opA[16 * t + ln] = f2bf((Acc[rowA * 68 + 16 * t + ln] + oaccA[t][r]) * irA);
        opB[16 * t + ln] = f2bf((Acc[rowB * 68 + 16 * t + ln] + oaccB[t][r]) * irB);
      }
    }
  }
}

// ---------------------------------------------------------------------------
extern "C" void kernel_launch(void* const* d_in, const int* in_sizes, int n_in,
                              void* d_out, int out_size, void* d_ws, size_t ws_size,
                              hipStream_t stream) {
  const float* q  = (const float*)d_in[0];
  const float* wq = (const float*)d_in[1];
  const float* bq = (const float*)d_in[2];
  const float* wk = (const float*)d_in[3];
  const float* bk = (const float*)d_in[4];
  const float* wv = (const float*)d_in[5];
  const float* bv = (const float*)d_in[6];
  const float* wo = (const float*)d_in[7];
  const float* bo = (const float*)d_in[8];
  float* out = (float*)d_out;

  const size_t XSZ = (size_t)MTOT * INDIM;
  const size_t WSZ = (size_t)EMB * INDIM;
  const size_t QSZ = (size_t)BATCH * NHEADS * SEQ * DH;
  ushort* wsX = (ushort*)d_ws;
  ushort* wsW = wsX + XSZ;
  ushort* wsQ = wsW + 4 * WSZ;
  ushort* wsK = wsQ + QSZ;
  ushort* wsVT = wsK + QSZ;
  ushort* wsA = wsVT + QSZ;   // attn output bf16 [B,N,EMB]

  const dim3 blk(256);

  const int nX = (int)(XSZ / 8);       // 524288 uint4
  const int nW = (int)(WSZ / 8);       // 32768 uint4 per weight matrix
  conv_all<<<dim3((nX + 4 * nW) / 256), blk, 0, stream>>>(
      q, wq, wk, wv, wo, wsX, wsW, nX, nW);

  mfma_gemm<0><<<dim3(MTOT / 128, 1536 / 128), blk, 0, stream>>>(
      wsX, wsW, bq, bk, bv, wsQ, wsK, wsVT, nullptr);

  attn_mfma<<<dim3(512), dim3(512), 0, stream>>>(wsQ, wsK, wsVT, wsA);

  mfma_gemm<1><<<dim3(MTOT / 64, EMB / 128), blk, 0, stream>>>(
      wsA, wsW + 3 * WSZ, bo, nullptr, nullptr, nullptr, nullptr, nullptr, out);
}

// Round 20
// 94.661 us; speedup vs baseline: 2.6131x; 1.0160x over previous
//
#include <hip/hip_runtime.h>
#include <hip/hip_bf16.h>
#include <math.h>

#define SEQ    2048
#define DH     64
#define EMB    512
#define INDIM  512
#define NHEADS 8
#define BATCH  4
#define MTOT   (BATCH * SEQ)   // 8192

typedef __attribute__((ext_vector_type(8))) short bf16x8;   // 8 bf16 = 4 VGPR
typedef __attribute__((ext_vector_type(4))) float f32x4;

__device__ __forceinline__ ushort f2bf(float x) {
  union { float f; unsigned u; } v; v.f = x;
  unsigned r = v.u + 0x7FFFu + ((v.u >> 16) & 1u);   // RNE
  return (ushort)(r >> 16);
}

// packed f32x2 -> bf16x2 (single HW op)
__device__ __forceinline__ unsigned cvt_pk_bf16(float lo, float hi) {
  unsigned r;
  asm("v_cvt_pk_bf16_f32 %0, %1, %2" : "=v"(r) : "v"(lo), "v"(hi));
  return r;
}

// raw v_exp_f32 (exp2); args bounded (static-max softmax)
__device__ __forceinline__ float fast_exp2(float x) {
  float r;
  asm("v_exp_f32 %0, %1" : "=v"(r) : "v"(x));
  return r;
}

// v_permlane32_swap_b32: after: x = [x.h0, y.h0], y = [x.h1, y.h1] (lane halves)
__device__ __forceinline__ void permswap32(unsigned &x, unsigned &y) {
  asm("v_permlane32_swap_b32 %0, %1" : "+v"(x), "+v"(y));
}

// ---------------------------------------------------------------------------
// Fused f32 -> bf16 conversion for X + the 4 weight matrices, ONE launch.
// Flat uint4 index space: [0, nX) -> X; [nX, nX + 4*nW) -> weights.
// ---------------------------------------------------------------------------
__global__ __launch_bounds__(256) void conv_all(
    const float* __restrict__ x, const float* __restrict__ w0,
    const float* __restrict__ w1, const float* __restrict__ w2,
    const float* __restrict__ w3,
    ushort* __restrict__ dstX, ushort* __restrict__ dstW,
    int nX, int nW) {
  const int i = blockIdx.x * 256 + threadIdx.x;
  const float* src;
  ushort* dst;
  int idx;
  if (i < nX) {
    src = x; dst = dstX; idx = i;
  } else {
    const int j = i - nX;
    const int w = j / nW;        // 0..3 (uniform per block)
    idx = j - w * nW;
    src = (w == 0) ? w0 : (w == 1) ? w1 : (w == 2) ? w2 : w3;
    dst = dstW + (size_t)w * nW * 8;
  }
  const float4 a = ((const float4*)src)[idx * 2];
  const float4 b = ((const float4*)src)[idx * 2 + 1];
  uint4 o;
  o.x = cvt_pk_bf16(a.x, a.y);
  o.y = cvt_pk_bf16(a.z, a.w);
  o.z = cvt_pk_bf16(b.x, b.y);
  o.w = cvt_pk_bf16(b.z, b.w);
  ((uint4*)dst)[idx] = o;
}

// ---------------------------------------------------------------------------
// MFMA GEMM, m97 structure, BK=32, 4 waves, global_load_lds width 16.
// MODE 0: 128x128 tile. Fused QKV (N=1536). which=bn>>9: 0->Q (pre-scaled
//         by 0.125*log2e), 1->K bf16 [B,H,N,Dh] (coalesced via LDS re-stage);
//         2->V^T bf16 [B,H,Dh,N] via LDS transpose.
// MODE 1: 64x128 tile (grid 512 = 2 blocks/CU). f32 out [M][EMB]+bias.
// ---------------------------------------------------------------------------
template <int MODE>
__global__ __launch_bounds__(256) void mfma_gemm(
    const ushort* __restrict__ A, const ushort* __restrict__ W,
    const float* __restrict__ b0, const float* __restrict__ b1,
    const float* __restrict__ b2,
    ushort* __restrict__ outQ, ushort* __restrict__ outK,
    ushort* __restrict__ outVT, float* __restrict__ outF) {
  constexpr int BM = (MODE == 0) ? 128 : 64;
  constexpr int MF = (MODE == 0) ? 4 : 2;       // m-frags per wave
  __shared__ __align__(16) char smem[MODE == 0 ? 35840 : 12288];
  ushort* As = (ushort*)smem;                         // [BM][32]
  ushort* Bs = (ushort*)(smem + (MODE == 0 ? 8192 : 4096));  // [128][32]
  ushort* Tl = (ushort*)smem;            // V epilogue transpose [128][140]
  ushort* Tl2 = (ushort*)smem;           // Q/K epilogue stage [128][136]

  const int bm = blockIdx.x * BM;
  const int bn = blockIdx.y * 128;
  const int tid = threadIdx.x;
  const int wave = tid >> 6, lane = tid & 63;
  const int g = lane >> 4, ln = lane & 15;
  const int wr = wave >> 1, wc = wave & 1;

  f32x4 acc[MF][4];
#pragma unroll
  for (int m = 0; m < MF; ++m)
#pragma unroll
    for (int n = 0; n < 4; ++n) acc[m][n] = (f32x4){0.f, 0.f, 0.f, 0.f};

  const size_t a_base = (size_t)(bm + wave * 16 + (lane >> 2)) * INDIM + (lane & 3) * 8;
  const size_t b_base = (size_t)(bn + wave * 16 + (lane >> 2)) * INDIM + (lane & 3) * 8;
  ushort* ldsA0 = As + wave * 512;
  ushort* ldsA1 = As + 2048 + wave * 512;
  ushort* ldsB0 = Bs + wave * 512;
  ushort* ldsB1 = Bs + 2048 + wave * 512;

  for (int k0 = 0; k0 < INDIM; k0 += 32) {
    __syncthreads();
    __builtin_amdgcn_global_load_lds(
        (const __attribute__((address_space(1))) void*)(A + a_base + k0),
        (__attribute__((address_space(3))) void*)ldsA0, 16, 0, 0);
    if (MODE == 0)
      __builtin_amdgcn_global_load_lds(
          (const __attribute__((address_space(1))) void*)(A + a_base + 64 * INDIM + k0),
          (__attribute__((address_space(3))) void*)ldsA1, 16, 0, 0);
    __builtin_amdgcn_global_load_lds(
        (const __attribute__((address_space(1))) void*)(W + b_base + k0),
        (__attribute__((address_space(3))) void*)ldsB0, 16, 0, 0);
    __builtin_amdgcn_global_load_lds(
        (const __attribute__((address_space(1))) void*)(W + b_base + 64 * INDIM + k0),
        (__attribute__((address_space(3))) void*)ldsB1, 16, 0, 0);
    __syncthreads();

    bf16x8 af[MF], bfv[4];
#pragma unroll
    for (int m = 0; m < MF; ++m)
      af[m] = *(const bf16x8*)&As[((MODE == 0 ? 64 : 32) * wr + 16 * m + ln) * 32 + 8 * g];
#pragma unroll
    for (int n = 0; n < 4; ++n)
      bfv[n] = *(const bf16x8*)&Bs[(64 * wc + 16 * n + ln) * 32 + 8 * g];
#pragma unroll
    for (int m = 0; m < MF; ++m)
#pragma unroll
      for (int n = 0; n < 4; ++n)
        acc[m][n] = __builtin_amdgcn_mfma_f32_16x16x32_bf16(af[m], bfv[n], acc[m][n], 0, 0, 0);
  }

  // ---- epilogue ----
  if (MODE == 1) {
#pragma unroll
    for (int n = 0; n < 4; ++n) {
      const int e = bn + 64 * wc + 16 * n + ln;
      const float bv = b0[e];
#pragma unroll
      for (int m = 0; m < MF; ++m)
#pragma unroll
        for (int r = 0; r < 4; ++r) {
          const int row = bm + 32 * wr + 16 * m + 4 * g + r;
          outF[(size_t)row * EMB + e] = acc[m][n][r] + bv;
        }
    }
    return;
  }

  const int which = bn >> 9;
  const float* bias = (which == 0) ? b0 : (which == 1) ? b1 : b2;

  if (which < 2) {
    // Q gets the softmax scale folded in (log2 domain): 0.125 * log2(e)
    const float scl = (which == 0) ? 0.18033688f : 1.0f;
    ushort* dst = (which == 0) ? outQ : outK;
    __syncthreads();   // As/Bs reads done; reuse smem as Tl2[128][136]
#pragma unroll
    for (int n = 0; n < 4; ++n) {
      const int cl = 64 * wc + 16 * n + ln;
      const float bv = bias[(bn & 511) + cl];
#pragma unroll
      for (int m = 0; m < 4; ++m)
#pragma unroll
        for (int r = 0; r < 4; ++r) {
          const int rl = 64 * wr + 16 * m + 4 * g + r;
          Tl2[rl * 136 + cl] = f2bf((acc[m][n][r] + bv) * scl);
        }
    }
    __syncthreads();
    // coalesced write-out: 256 segments of 128B (row rl x head-half)
#pragma unroll
    for (int j = 0; j < 8; ++j) {
      const int cid = j * 256 + tid;      // 0..2047
      const int seg = cid >> 3;           // 0..255
      const int l8 = cid & 7;
      const int rl = seg >> 1, half = seg & 1;
      const int row = bm + rl;
      const int b = row >> 11, nn = row & (SEQ - 1);
      const int h = ((bn & 511) >> 6) + half;
      const bf16x8 v = *(const bf16x8*)&Tl2[rl * 136 + half * 64 + l8 * 8];
      *(bf16x8*)&dst[(((size_t)(b * NHEADS + h) * SEQ) + nn) * DH + l8 * 8] = v;
    }
  } else {
    // V: transpose through LDS, write V^T [B,H,Dh,N]
    __syncthreads();
#pragma unroll
    for (int n = 0; n < 4; ++n) {
      const int cl = 64 * wc + 16 * n + ln;
      const float bv = bias[(bn & 511) + cl];
#pragma unroll
      for (int m = 0; m < 4; ++m)
#pragma unroll
        for (int r = 0; r < 4; ++r) {
          const int rl = 64 * wr + 16 * m + 4 * g + r;
          Tl[cl * 140 + rl] = f2bf(acc[m][n][r] + bv);
        }
    }
    __syncthreads();
    const int c = tid >> 1;
    const int rh = (tid & 1) * 64;
    const int e = (bn & 511) + c;
    const int h = e >> 6, d = e & 63;
    const int b = bm >> 11;
    const int nn0 = (bm & (SEQ - 1)) + rh;
    ushort* drow = outVT + (((size_t)(b * NHEADS + h) * DH) + d) * SEQ + nn0;
#pragma unroll
    for (int j = 0; j < 8; ++j)
      *(bf16x8*)&drow[j * 8] = *(const bf16x8*)&Tl[c * 140 + rh + j * 8];
  }
}

// ---------------------------------------------------------------------------
// MFMA flash attention: IN-BLOCK kv-split x2, SINGLE-BUFFERED LDS (36.9 KB).
// Occupancy-residency experiment: R18's 73.7KB double-buffer measured only
// ~19% occupancy (~1 block/CU resident despite 2 fitting on paper). Halving
// LDS to 36.9KB makes multi-block residency unambiguous (<=4 blocks/CU).
// Sync reverts to the R12-verified single-buffer pattern: __syncthreads ->
// LDS write -> prefetch regs -> lgkmcnt(0)+s_barrier -> compute (2 barriers
// per iter; R15 measured that extra barrier costs only ~1.3us).
// Both halves run identical iteration counts so block-wide barriers align.
// Everything else R19-verbatim: merged-phase A/B body, ones-MFMA denominator,
// in-register P (pi-permuted K staging + cvt_pk + permlane32_swap),
// static-max exp2 softmax (Q pre-scaled by 0.125*log2e), XCD swizzle,
// LDS-overlay combine, bf16 O.
// ---------------------------------------------------------------------------
__global__ __launch_bounds__(512, 2) void attn_mfma(const ushort* __restrict__ Q,
                                                    const ushort* __restrict__ K,
                                                    const ushort* __restrict__ VT,
                                                    ushort* __restrict__ O) {
  // layout: K0 [0,9216) | K1 [9216,18432) | V0 [18432,27648) | V1 [27648,36864)
  __shared__ __align__(16) char smem[36864];

  const int tid = threadIdx.x;
  const int half = tid >> 8;            // kv half
  const int ltid = tid & 255;           // local tid within half
  const int wave = ltid >> 6, lane = ltid & 63;
  const int g = lane >> 4, ln = lane & 15;

  ushort* Kh = (ushort*)(smem + half * 9216);
  ushort* Vh = (ushort*)(smem + 18432 + half * 9216);

  // XCD swizzle over 512 wgs: swz = (orig%8)*64 + orig/8 (bijective; 4 bh/XCD)
  const int orig = blockIdx.x;
  const int swz = (orig & 7) * 64 + (orig >> 3);
  const int bh = swz >> 4;            // 0..31
  const int qx = swz & 15;            // 0..15
  const int qbase = qx * 128 + wave * 32;
  const int kvbase = half << 10;      // 0 or 1024

  const ushort* Qb = Q + ((size_t)bh * SEQ + qbase) * DH;
  const ushort* Kb = K + (size_t)bh * SEQ * DH;
  const ushort* Vb = VT + (size_t)bh * DH * SEQ;

  const bf16x8 qfA0 = *(const bf16x8*)&Qb[ln * DH + 8 * g];
  const bf16x8 qfA1 = *(const bf16x8*)&Qb[ln * DH + 32 + 8 * g];
  const bf16x8 qfB0 = *(const bf16x8*)&Qb[(16 + ln) * DH + 8 * g];
  const bf16x8 qfB1 = *(const bf16x8*)&Qb[(16 + ln) * DH + 32 + 8 * g];

  // ones B-fragment for the denominator MFMA (bf16 1.0 = 0x3F80)
  bf16x8 vones;
#pragma unroll
  for (int i = 0; i < 8; ++i) vones[i] = (short)0x3F80;

  f32x4 oaccA[4], oaccB[4];
  f32x4 oaccDA = (f32x4){0.f, 0.f, 0.f, 0.f};
  f32x4 oaccDB = (f32x4){0.f, 0.f, 0.f, 0.f};
#pragma unroll
  for (int t = 0; t < 4; ++t) {
    oaccA[t] = (f32x4){0.f, 0.f, 0.f, 0.f};
    oaccB[t] = (f32x4){0.f, 0.f, 0.f, 0.f};
  }

  const int skv = ltid >> 3, sd = (ltid & 7) * 8;   // K staging (rows skv, skv+32)
  const int dt = ltid >> 2, kc = (ltid & 3) * 8;    // V staging
  // pi-permuted LDS rows for K: XOR 12 where bit2^bit3 (swaps rows 4-7 <-> 8-11)
  const int pr0 = skv ^ (((((skv >> 2) ^ (skv >> 3)) & 1)) * 12);
  const int s32 = skv + 32;
  const int pr1 = s32 ^ (((((s32 >> 2) ^ (s32 >> 3)) & 1)) * 12);

  // ---- preload tile 0 into regs ----
  bf16x8 k0v = *(const bf16x8*)&Kb[(size_t)(kvbase + skv) * DH + sd];
  bf16x8 k1v = *(const bf16x8*)&Kb[(size_t)(kvbase + 32 + skv) * DH + sd];
  bf16x8 v0v = *(const bf16x8*)&Vb[(size_t)dt * SEQ + kvbase + kc];
  bf16x8 v1v = *(const bf16x8*)&Vb[(size_t)dt * SEQ + kvbase + 32 + kc];

  for (int it = 0; it < 16; ++it) {
    __syncthreads();   // prev iter's LDS reads complete
    *(bf16x8*)&Kh[pr0 * 72 + sd] = k0v;
    *(bf16x8*)&Kh[pr1 * 72 + sd] = k1v;
    *(bf16x8*)&Vh[dt * 72 + kc] = v0v;
    *(bf16x8*)&Vh[dt * 72 + 32 + kc] = v1v;

    // prefetch tile it+1 (clamped; redundant tail loads harmless)
    {
      const int nxt = kvbase + ((it + 1 < 16) ? (it + 1) * 64 : 15 * 64);
      k0v = *(const bf16x8*)&Kb[(size_t)(nxt + skv) * DH + sd];
      k1v = *(const bf16x8*)&Kb[(size_t)(nxt + 32 + skv) * DH + sd];
      v0v = *(const bf16x8*)&Vb[(size_t)dt * SEQ + nxt + kc];
      v1v = *(const bf16x8*)&Vb[(size_t)dt * SEQ + nxt + 32 + kc];
    }

    asm volatile("s_waitcnt lgkmcnt(0)" ::: "memory");
    __builtin_amdgcn_s_barrier();

    // ---- shared fragments, read ONCE, reused by both q-groups ----
    bf16x8 ka[4][2], vb[2][4];
#pragma unroll
    for (int t = 0; t < 4; ++t) {
      ka[t][0] = *(const bf16x8*)&Kh[(16 * t + ln) * 72 + 8 * g];
      ka[t][1] = *(const bf16x8*)&Kh[(16 * t + ln) * 72 + 32 + 8 * g];
    }
#pragma unroll
    for (int c = 0; c < 2; ++c)
#pragma unroll
      for (int t = 0; t < 4; ++t)
        vb[c][t] = *(const bf16x8*)&Vh[(16 * t + ln) * 72 + 32 * c + 8 * g];

    // ---- QK^T, BOTH groups in one batch (8 independent acc chains) ----
    f32x4 sA0 = (f32x4){0.f, 0.f, 0.f, 0.f};
    f32x4 sA1 = sA0, sA2 = sA0, sA3 = sA0;
    f32x4 sB0 = sA0, sB1 = sA0, sB2 = sA0, sB3 = sA0;
    __builtin_amdgcn_s_setprio(1);
    sA0 = __builtin_amdgcn_mfma_f32_16x16x32_bf16(ka[0][0], qfA0, sA0, 0, 0, 0);
    sB0 = __builtin_amdgcn_mfma_f32_16x16x32_bf16(ka[0][0], qfB0, sB0, 0, 0, 0);
    sA1 = __builtin_amdgcn_mfma_f32_16x16x32_bf16(ka[1][0], qfA0, sA1, 0, 0, 0);
    sB1 = __builtin_amdgcn_mfma_f32_16x16x32_bf16(ka[1][0], qfB0, sB1, 0, 0, 0);
    sA2 = __builtin_amdgcn_mfma_f32_16x16x32_bf16(ka[2][0], qfA0, sA2, 0, 0, 0);
    sB2 = __builtin_amdgcn_mfma_f32_16x16x32_bf16(ka[2][0], qfB0, sB2, 0, 0, 0);
    sA3 = __builtin_amdgcn_mfma_f32_16x16x32_bf16(ka[3][0], qfA0, sA3, 0, 0, 0);
    sB3 = __builtin_amdgcn_mfma_f32_16x16x32_bf16(ka[3][0], qfB0, sB3, 0, 0, 0);
    sA0 = __builtin_amdgcn_mfma_f32_16x16x32_bf16(ka[0][1], qfA1, sA0, 0, 0, 0);
    sB0 = __builtin_amdgcn_mfma_f32_16x16x32_bf16(ka[0][1], qfB1, sB0, 0, 0, 0);
    sA1 = __builtin_amdgcn_mfma_f32_16x16x32_bf16(ka[1][1], qfA1, sA1, 0, 0, 0);
    sB1 = __builtin_amdgcn_mfma_f32_16x16x32_bf16(ka[1][1], qfB1, sB1, 0, 0, 0);
    sA2 = __builtin_amdgcn_mfma_f32_16x16x32_bf16(ka[2][1], qfA1, sA2, 0, 0, 0);
    sB2 = __builtin_amdgcn_mfma_f32_16x16x32_bf16(ka[2][1], qfB1, sB2, 0, 0, 0);
    sA3 = __builtin_amdgcn_mfma_f32_16x16x32_bf16(ka[3][1], qfA1, sA3, 0, 0, 0);
    sB3 = __builtin_amdgcn_mfma_f32_16x16x32_bf16(ka[3][1], qfB1, sB3, 0, 0, 0);
    __builtin_amdgcn_s_setprio(0);

    // ---- P = exp2(S), BOTH groups (32 independent trans ops) ----
    float pA0[4], pA1[4], pA2[4], pA3[4];
    float pB0[4], pB1[4], pB2[4], pB3[4];
#pragma unroll
    for (int r = 0; r < 4; ++r) {
      pA0[r] = fast_exp2(sA0[r]);
      pA1[r] = fast_exp2(sA1[r]);
      pA2[r] = fast_exp2(sA2[r]);
      pA3[r] = fast_exp2(sA3[r]);
      pB0[r] = fast_exp2(sB0[r]);
      pB1[r] = fast_exp2(sB1[r]);
      pB2[r] = fast_exp2(sB2[r]);
      pB3[r] = fast_exp2(sB3[r]);
    }

    // ---- pack + permlane -> PV A-fragments, BOTH groups (no LDS) ----
    unsigned aa0 = cvt_pk_bf16(pA0[0], pA0[1]);
    unsigned aa2 = cvt_pk_bf16(pA1[0], pA1[1]);
    unsigned aa1 = cvt_pk_bf16(pA0[2], pA0[3]);
    unsigned aa3 = cvt_pk_bf16(pA1[2], pA1[3]);
    permswap32(aa0, aa2);
    permswap32(aa1, aa3);
    unsigned ab0 = cvt_pk_bf16(pA2[0], pA2[1]);
    unsigned ab2 = cvt_pk_bf16(pA3[0], pA3[1]);
    unsigned ab1 = cvt_pk_bf16(pA2[2], pA2[3]);
    unsigned ab3 = cvt_pk_bf16(pA3[2], pA3[3]);
    permswap32(ab0, ab2);
    permswap32(ab1, ab3);
    unsigned ba0 = cvt_pk_bf16(pB0[0], pB0[1]);
    unsigned ba2 = cvt_pk_bf16(pB1[0], pB1[1]);
    unsigned ba1 = cvt_pk_bf16(pB0[2], pB0[3]);
    unsigned ba3 = cvt_pk_bf16(pB1[2], pB1[3]);
    permswap32(ba0, ba2);
    permswap32(ba1, ba3);
    unsigned bb0 = cvt_pk_bf16(pB2[0], pB2[1]);
    unsigned bb2 = cvt_pk_bf16(pB3[0], pB3[1]);
    unsigned bb1 = cvt_pk_bf16(pB2[2], pB2[3]);
    unsigned bb3 = cvt_pk_bf16(pB3[2], pB3[3]);
    permswap32(bb0, bb2);
    permswap32(bb1, bb3);
    union { unsigned u[4]; bf16x8 v; } paA0, paA1, paB0, paB1;
    paA0.u[0] = aa0; paA0.u[1] = aa1; paA0.u[2] = aa2; paA0.u[3] = aa3;
    paA1.u[0] = ab0; paA1.u[1] = ab1; paA1.u[2] = ab2; paA1.u[3] = ab3;
    paB0.u[0] = ba0; paB0.u[1] = ba1; paB0.u[2] = ba2; paB0.u[3] = ba3;
    paB1.u[0] = bb0; paB1.u[1] = bb1; paB1.u[2] = bb2; paB1.u[3] = bb3;

    // ---- PV + denominators, BOTH groups in one MFMA batch ----
    __builtin_amdgcn_s_setprio(1);
#pragma unroll
    for (int t = 0; t < 4; ++t) {
      oaccA[t] = __builtin_amdgcn_mfma_f32_16x16x32_bf16(paA0.v, vb[0][t], oaccA[t], 0, 0, 0);
      oaccB[t] = __builtin_amdgcn_mfma_f32_16x16x32_bf16(paB0.v, vb[0][t], oaccB[t], 0, 0, 0);
      oaccA[t] = __builtin_amdgcn_mfma_f32_16x16x32_bf16(paA1.v, vb[1][t], oaccA[t], 0, 0, 0);
      oaccB[t] = __builtin_amdgcn_mfma_f32_16x16x32_bf16(paB1.v, vb[1][t], oaccB[t], 0, 0, 0);
    }
    oaccDA = __builtin_amdgcn_mfma_f32_16x16x32_bf16(paA0.v, vones, oaccDA, 0, 0, 0);
    oaccDB = __builtin_amdgcn_mfma_f32_16x16x32_bf16(paB0.v, vones, oaccDB, 0, 0, 0);
    oaccDA = __builtin_amdgcn_mfma_f32_16x16x32_bf16(paA1.v, vones, oaccDA, 0, 0, 0);
    oaccDB = __builtin_amdgcn_mfma_f32_16x16x32_bf16(paB1.v, vones, oaccDB, 0, 0, 0);
    __builtin_amdgcn_s_setprio(0);
  }

  // ---- combine halves through LDS overlay (K/V buffers are dead) ----
  float* Acc = (float*)smem;                 // [128][68] f32 = 34816B
  float* Dl  = (float*)(smem + 34816);       // [128] f32 = 512B (<=36864)
  __syncthreads();
  if (half == 0) {
#pragma unroll
    for (int t = 0; t < 4; ++t)
#pragma unroll
      for (int r = 0; r < 4; ++r) {
        Acc[(wave * 32 + 4 * g + r) * 68 + 16 * t + ln] = oaccA[t][r];
        Acc[(wave * 32 + 16 + 4 * g + r) * 68 + 16 * t + ln] = oaccB[t][r];
      }
    if (ln == 0) {
#pragma unroll
      for (int r = 0; r < 4; ++r) {
        Dl[wave * 32 + 4 * g + r] = oaccDA[r];
        Dl[wave * 32 + 16 + 4 * g + r] = oaccDB[r];
      }
    }
  }
  __syncthreads();
  if (half == 1) {
    const int b = bh >> 3, h = bh & 7;
#pragma unroll
    for (int r = 0; r < 4; ++r) {
      const int rowA = wave * 32 + 4 * g + r;
      const int rowB = rowA + 16;
      const float irA = 1.0f / (Dl[rowA] + oaccDA[r]);
      const float irB = 1.0f / (Dl[rowB] + oaccDB[r]);
      ushort* opA = O + ((size_t)(b * SEQ) + qx * 128 + rowA) * EMB + h * 64;
      ushort* opB = O + ((size_t)(b * SEQ) + qx * 128 + rowB) * EMB + h * 64;
#pragma unroll
      for (int t = 0; t < 4; ++t) {
        opA[16 * t + ln] = f2bf((Acc[rowA * 68 + 16 * t + ln] + oaccA[t][r]) * irA);
        opB[16 * t + ln] = f2bf((Acc[rowB * 68 + 16 * t + ln] + oaccB[t][r]) * irB);
      }
    }
  }
}

// ---------------------------------------------------------------------------
extern "C" void kernel_launch(void* const* d_in, const int* in_sizes, int n_in,
                              void* d_out, int out_size, void* d_ws, size_t ws_size,
                              hipStream_t stream) {
  const float* q  = (const float*)d_in[0];
  const float* wq = (const float*)d_in[1];
  const float* bq = (const float*)d_in[2];
  const float* wk = (const float*)d_in[3];
  const float* bk = (const float*)d_in[4];
  const float* wv = (const float*)d_in[5];
  const float* bv = (const float*)d_in[6];
  const float* wo = (const float*)d_in[7];
  const float* bo = (const float*)d_in[8];
  float* out = (float*)d_out;

  const size_t XSZ = (size_t)MTOT * INDIM;
  const size_t WSZ = (size_t)EMB * INDIM;
  const size_t QSZ = (size_t)BATCH * NHEADS * SEQ * DH;
  ushort* wsX = (ushort*)d_ws;
  ushort* wsW = wsX + XSZ;
  ushort* wsQ = wsW + 4 * WSZ;
  ushort* wsK = wsQ + QSZ;
  ushort* wsVT = wsK + QSZ;
  ushort* wsA = wsVT + QSZ;   // attn output bf16 [B,N,EMB]

  const dim3 blk(256);

  const int nX = (int)(XSZ / 8);       // 524288 uint4
  const int nW = (int)(WSZ / 8);       // 32768 uint4 per weight matrix
  conv_all<<<dim3((nX + 4 * nW) / 256), blk, 0, stream>>>(
      q, wq, wk, wv, wo, wsX, wsW, nX, nW);

  mfma_gemm<0><<<dim3(MTOT / 128, 1536 / 128), blk, 0, stream>>>(
      wsX, wsW, bq, bk, bv, wsQ, wsK, wsVT, nullptr);

  attn_mfma<<<dim3(512), dim3(512), 0, stream>>>(wsQ, wsK, wsVT, wsA);

  mfma_gemm<1><<<dim3(MTOT / 64, EMB / 128), blk, 0, stream>>>(
      wsA, wsW + 3 * WSZ, bo, nullptr, nullptr, nullptr, nullptr, nullptr, out);
}

// Round 22
// 94.402 us; speedup vs baseline: 2.6203x; 1.0027x over previous
//
#include <hip/hip_runtime.h>
#include <hip/hip_bf16.h>
#include <math.h>

#define SEQ    2048
#define DH     64
#define EMB    512
#define INDIM  512
#define NHEADS 8
#define BATCH  4
#define MTOT   (BATCH * SEQ)   // 8192

typedef __attribute__((ext_vector_type(8))) short bf16x8;   // 8 bf16 = 4 VGPR
typedef __attribute__((ext_vector_type(4))) float f32x4;

__device__ __forceinline__ ushort f2bf(float x) {
  union { float f; unsigned u; } v; v.f = x;
  unsigned r = v.u + 0x7FFFu + ((v.u >> 16) & 1u);   // RNE
  return (ushort)(r >> 16);
}

// packed f32x2 -> bf16x2 (single HW op)
__device__ __forceinline__ unsigned cvt_pk_bf16(float lo, float hi) {
  unsigned r;
  asm("v_cvt_pk_bf16_f32 %0, %1, %2" : "=v"(r) : "v"(lo), "v"(hi));
  return r;
}

// raw v_exp_f32 (exp2); args bounded (static-max softmax)
__device__ __forceinline__ float fast_exp2(float x) {
  float r;
  asm("v_exp_f32 %0, %1" : "=v"(r) : "v"(x));
  return r;
}

// v_permlane32_swap_b32: after: x = [x.h0, y.h0], y = [x.h1, y.h1] (lane halves)
__device__ __forceinline__ void permswap32(unsigned &x, unsigned &y) {
  asm("v_permlane32_swap_b32 %0, %1" : "+v"(x), "+v"(y));
}

// ---------------------------------------------------------------------------
// Fused f32 -> bf16 conversion for X + the 4 weight matrices, ONE launch.
// Flat uint4 index space: [0, nX) -> X; [nX, nX + 4*nW) -> weights.
// ---------------------------------------------------------------------------
__global__ __launch_bounds__(256) void conv_all(
    const float* __restrict__ x, const float* __restrict__ w0,
    const float* __restrict__ w1, const float* __restrict__ w2,
    const float* __restrict__ w3,
    ushort* __restrict__ dstX, ushort* __restrict__ dstW,
    int nX, int nW) {
  const int i = blockIdx.x * 256 + threadIdx.x;
  const float* src;
  ushort* dst;
  int idx;
  if (i < nX) {
    src = x; dst = dstX; idx = i;
  } else {
    const int j = i - nX;
    const int w = j / nW;        // 0..3 (uniform per block)
    idx = j - w * nW;
    src = (w == 0) ? w0 : (w == 1) ? w1 : (w == 2) ? w2 : w3;
    dst = dstW + (size_t)w * nW * 8;
  }
  const float4 a = ((const float4*)src)[idx * 2];
  const float4 b = ((const float4*)src)[idx * 2 + 1];
  uint4 o;
  o.x = cvt_pk_bf16(a.x, a.y);
  o.y = cvt_pk_bf16(a.z, a.w);
  o.z = cvt_pk_bf16(b.x, b.y);
  o.w = cvt_pk_bf16(b.z, b.w);
  ((uint4*)dst)[idx] = o;
}

// ---------------------------------------------------------------------------
// MFMA GEMM, m97 structure, BK=32, 4 waves, global_load_lds width 16.
// MODE 0: 128x128 tile. Fused QKV (N=1536). which=bn>>9: 0->Q (pre-scaled
//         by 0.125*log2e), 1->K bf16 [B,H,N,Dh] (coalesced via LDS re-stage);
//         2->V^T bf16 [B,H,Dh,N] via LDS transpose.
// MODE 1: 64x128 tile (grid 512 = 2 blocks/CU). f32 out [M][EMB]+bias.
// ---------------------------------------------------------------------------
template <int MODE>
__global__ __launch_bounds__(256) void mfma_gemm(
    const ushort* __restrict__ A, const ushort* __restrict__ W,
    const float* __restrict__ b0, const float* __restrict__ b1,
    const float* __restrict__ b2,
    ushort* __restrict__ outQ, ushort* __restrict__ outK,
    ushort* __restrict__ outVT, float* __restrict__ outF) {
  constexpr int BM = (MODE == 0) ? 128 : 64;
  constexpr int MF = (MODE == 0) ? 4 : 2;       // m-frags per wave
  __shared__ __align__(16) char smem[MODE == 0 ? 35840 : 12288];
  ushort* As = (ushort*)smem;                         // [BM][32]
  ushort* Bs = (ushort*)(smem + (MODE == 0 ? 8192 : 4096));  // [128][32]
  ushort* Tl = (ushort*)smem;            // V epilogue transpose [128][140]
  ushort* Tl2 = (ushort*)smem;           // Q/K epilogue stage [128][136]

  const int bm = blockIdx.x * BM;
  const int bn = blockIdx.y * 128;
  const int tid = threadIdx.x;
  const int wave = tid >> 6, lane = tid & 63;
  const int g = lane >> 4, ln = lane & 15;
  const int wr = wave >> 1, wc = wave & 1;

  f32x4 acc[MF][4];
#pragma unroll
  for (int m = 0; m < MF; ++m)
#pragma unroll
    for (int n = 0; n < 4; ++n) acc[m][n] = (f32x4){0.f, 0.f, 0.f, 0.f};

  const size_t a_base = (size_t)(bm + wave * 16 + (lane >> 2)) * INDIM + (lane & 3) * 8;
  const size_t b_base = (size_t)(bn + wave * 16 + (lane >> 2)) * INDIM + (lane & 3) * 8;
  ushort* ldsA0 = As + wave * 512;
  ushort* ldsA1 = As + 2048 + wave * 512;
  ushort* ldsB0 = Bs + wave * 512;
  ushort* ldsB1 = Bs + 2048 + wave * 512;

  for (int k0 = 0; k0 < INDIM; k0 += 32) {
    __syncthreads();
    __builtin_amdgcn_global_load_lds(
        (const __attribute__((address_space(1))) void*)(A + a_base + k0),
        (__attribute__((address_space(3))) void*)ldsA0, 16, 0, 0);
    if (MODE == 0)
      __builtin_amdgcn_global_load_lds(
          (const __attribute__((address_space(1))) void*)(A + a_base + 64 * INDIM + k0),
          (__attribute__((address_space(3))) void*)ldsA1, 16, 0, 0);
    __builtin_amdgcn_global_load_lds(
        (const __attribute__((address_space(1))) void*)(W + b_base + k0),
        (__attribute__((address_space(3))) void*)ldsB0, 16, 0, 0);
    __builtin_amdgcn_global_load_lds(
        (const __attribute__((address_space(1))) void*)(W + b_base + 64 * INDIM + k0),
        (__attribute__((address_space(3))) void*)ldsB1, 16, 0, 0);
    __syncthreads();

    bf16x8 af[MF], bfv[4];
#pragma unroll
    for (int m = 0; m < MF; ++m)
      af[m] = *(const bf16x8*)&As[((MODE == 0 ? 64 : 32) * wr + 16 * m + ln) * 32 + 8 * g];
#pragma unroll
    for (int n = 0; n < 4; ++n)
      bfv[n] = *(const bf16x8*)&Bs[(64 * wc + 16 * n + ln) * 32 + 8 * g];
#pragma unroll
    for (int m = 0; m < MF; ++m)
#pragma unroll
      for (int n = 0; n < 4; ++n)
        acc[m][n] = __builtin_amdgcn_mfma_f32_16x16x32_bf16(af[m], bfv[n], acc[m][n], 0, 0, 0);
  }

  // ---- epilogue ----
  if (MODE == 1) {
#pragma unroll
    for (int n = 0; n < 4; ++n) {
      const int e = bn + 64 * wc + 16 * n + ln;
      const float bv = b0[e];
#pragma unroll
      for (int m = 0; m < MF; ++m)
#pragma unroll
        for (int r = 0; r < 4; ++r) {
          const int row = bm + 32 * wr + 16 * m + 4 * g + r;
          outF[(size_t)row * EMB + e] = acc[m][n][r] + bv;
        }
    }
    return;
  }

  const int which = bn >> 9;
  const float* bias = (which == 0) ? b0 : (which == 1) ? b1 : b2;

  if (which < 2) {
    // Q gets the softmax scale folded in (log2 domain): 0.125 * log2(e)
    const float scl = (which == 0) ? 0.18033688f : 1.0f;
    ushort* dst = (which == 0) ? outQ : outK;
    __syncthreads();   // As/Bs reads done; reuse smem as Tl2[128][136]
#pragma unroll
    for (int n = 0; n < 4; ++n) {
      const int cl = 64 * wc + 16 * n + ln;
      const float bv = bias[(bn & 511) + cl];
#pragma unroll
      for (int m = 0; m < 4; ++m)
#pragma unroll
        for (int r = 0; r < 4; ++r) {
          const int rl = 64 * wr + 16 * m + 4 * g + r;
          Tl2[rl * 136 + cl] = f2bf((acc[m][n][r] + bv) * scl);
        }
    }
    __syncthreads();
    // coalesced write-out: 256 segments of 128B (row rl x head-half)
#pragma unroll
    for (int j = 0; j < 8; ++j) {
      const int cid = j * 256 + tid;      // 0..2047
      const int seg = cid >> 3;           // 0..255
      const int l8 = cid & 7;
      const int rl = seg >> 1, half = seg & 1;
      const int row = bm + rl;
      const int b = row >> 11, nn = row & (SEQ - 1);
      const int h = ((bn & 511) >> 6) + half;
      const bf16x8 v = *(const bf16x8*)&Tl2[rl * 136 + half * 64 + l8 * 8];
      *(bf16x8*)&dst[(((size_t)(b * NHEADS + h) * SEQ) + nn) * DH + l8 * 8] = v;
    }
  } else {
    // V: transpose through LDS, write V^T [B,H,Dh,N]
    __syncthreads();
#pragma unroll
    for (int n = 0; n < 4; ++n) {
      const int cl = 64 * wc + 16 * n + ln;
      const float bv = bias[(bn & 511) + cl];
#pragma unroll
      for (int m = 0; m < 4; ++m)
#pragma unroll
        for (int r = 0; r < 4; ++r) {
          const int rl = 64 * wr + 16 * m + 4 * g + r;
          Tl[cl * 140 + rl] = f2bf(acc[m][n][r] + bv);
        }
    }
    __syncthreads();
    const int c = tid >> 1;
    const int rh = (tid & 1) * 64;
    const int e = (bn & 511) + c;
    const int h = e >> 6, d = e & 63;
    const int b = bm >> 11;
    const int nn0 = (bm & (SEQ - 1)) + rh;
    ushort* drow = outVT + (((size_t)(b * NHEADS + h) * DH) + d) * SEQ + nn0;
#pragma unroll
    for (int j = 0; j < 8; ++j)
      *(bf16x8*)&drow[j * 8] = *(const bf16x8*)&Tl[c * 140 + rh + j * 8];
  }
}

// ---------------------------------------------------------------------------
// MFMA flash attention: R20-verbatim (best verified: 53.6us, absmax 4.88e-4).
// In-block kv-split x2, single-buffered 36.9KB LDS, 2 barriers/iter.
// NOTE: the s_setprio(1)/(0) brackets are LOAD-BEARING as compiler scheduling
// fences -- R21 removed them and correctness broke (absmax 1.5e-2): without
// the opaque side-effecting builtins, hipcc reorders LDS fragment reads
// across the raw s_barrier (rule-#18 hazard class). DO NOT REMOVE.
// Merged-phase A/B body, ones-MFMA denominator, in-register P (pi-permuted
// K staging + cvt_pk + permlane32_swap), static-max exp2 softmax (Q
// pre-scaled by 0.125*log2e), XCD swizzle, LDS-overlay combine, bf16 O.
// ---------------------------------------------------------------------------
__global__ __launch_bounds__(512, 2) void attn_mfma(const ushort* __restrict__ Q,
                                                    const ushort* __restrict__ K,
                                                    const ushort* __restrict__ VT,
                                                    ushort* __restrict__ O) {
  // layout: K0 [0,9216) | K1 [9216,18432) | V0 [18432,27648) | V1 [27648,36864)
  __shared__ __align__(16) char smem[36864];

  const int tid = threadIdx.x;
  const int half = tid >> 8;            // kv half
  const int ltid = tid & 255;           // local tid within half
  const int wave = ltid >> 6, lane = ltid & 63;
  const int g = lane >> 4, ln = lane & 15;

  ushort* Kh = (ushort*)(smem + half * 9216);
  ushort* Vh = (ushort*)(smem + 18432 + half * 9216);

  // XCD swizzle over 512 wgs: swz = (orig%8)*64 + orig/8 (bijective; 4 bh/XCD)
  const int orig = blockIdx.x;
  const int swz = (orig & 7) * 64 + (orig >> 3);
  const int bh = swz >> 4;            // 0..31
  const int qx = swz & 15;            // 0..15
  const int qbase = qx * 128 + wave * 32;
  const int kvbase = half << 10;      // 0 or 1024

  const ushort* Qb = Q + ((size_t)bh * SEQ + qbase) * DH;
  const ushort* Kb = K + (size_t)bh * SEQ * DH;
  const ushort* Vb = VT + (size_t)bh * DH * SEQ;

  const bf16x8 qfA0 = *(const bf16x8*)&Qb[ln * DH + 8 * g];
  const bf16x8 qfA1 = *(const bf16x8*)&Qb[ln * DH + 32 + 8 * g];
  const bf16x8 qfB0 = *(const bf16x8*)&Qb[(16 + ln) * DH + 8 * g];
  const bf16x8 qfB1 = *(const bf16x8*)&Qb[(16 + ln) * DH + 32 + 8 * g];

  // ones B-fragment for the denominator MFMA (bf16 1.0 = 0x3F80)
  bf16x8 vones;
#pragma unroll
  for (int i = 0; i < 8; ++i) vones[i] = (short)0x3F80;

  f32x4 oaccA[4], oaccB[4];
  f32x4 oaccDA = (f32x4){0.f, 0.f, 0.f, 0.f};
  f32x4 oaccDB = (f32x4){0.f, 0.f, 0.f, 0.f};
#pragma unroll
  for (int t = 0; t < 4; ++t) {
    oaccA[t] = (f32x4){0.f, 0.f, 0.f, 0.f};
    oaccB[t] = (f32x4){0.f, 0.f, 0.f, 0.f};
  }

  const int skv = ltid >> 3, sd = (ltid & 7) * 8;   // K staging (rows skv, skv+32)
  const int dt = ltid >> 2, kc = (ltid & 3) * 8;    // V staging
  // pi-permuted LDS rows for K: XOR 12 where bit2^bit3 (swaps rows 4-7 <-> 8-11)
  const int pr0 = skv ^ (((((skv >> 2) ^ (skv >> 3)) & 1)) * 12);
  const int s32 = skv + 32;
  const int pr1 = s32 ^ (((((s32 >> 2) ^ (s32 >> 3)) & 1)) * 12);

  // ---- preload tile 0 into regs ----
  bf16x8 k0v = *(const bf16x8*)&Kb[(size_t)(kvbase + skv) * DH + sd];
  bf16x8 k1v = *(const bf16x8*)&Kb[(size_t)(kvbase + 32 + skv) * DH + sd];
  bf16x8 v0v = *(const bf16x8*)&Vb[(size_t)dt * SEQ + kvbase + kc];
  bf16x8 v1v = *(const bf16x8*)&Vb[(size_t)dt * SEQ + kvbase + 32 + kc];

  for (int it = 0; it < 16; ++it) {
    __syncthreads();   // prev iter's LDS reads complete
    *(bf16x8*)&Kh[pr0 * 72 + sd] = k0v;
    *(bf16x8*)&Kh[pr1 * 72 + sd] = k1v;
    *(bf16x8*)&Vh[dt * 72 + kc] = v0v;
    *(bf16x8*)&Vh[dt * 72 + 32 + kc] = v1v;

    // prefetch tile it+1 (clamped; redundant tail loads harmless)
    {
      const int nxt = kvbase + ((it + 1 < 16) ? (it + 1) * 64 : 15 * 64);
      k0v = *(const bf16x8*)&Kb[(size_t)(nxt + skv) * DH + sd];
      k1v = *(const bf16x8*)&Kb[(size_t)(nxt + 32 + skv) * DH + sd];
      v0v = *(const bf16x8*)&Vb[(size_t)dt * SEQ + nxt + kc];
      v1v = *(const bf16x8*)&Vb[(size_t)dt * SEQ + nxt + 32 + kc];
    }

    asm volatile("s_waitcnt lgkmcnt(0)" ::: "memory");
    __builtin_amdgcn_s_barrier();

    // ---- shared fragments, read ONCE, reused by both q-groups ----
    bf16x8 ka[4][2], vb[2][4];
#pragma unroll
    for (int t = 0; t < 4; ++t) {
      ka[t][0] = *(const bf16x8*)&Kh[(16 * t + ln) * 72 + 8 * g];
      ka[t][1] = *(const bf16x8*)&Kh[(16 * t + ln) * 72 + 32 + 8 * g];
    }
#pragma unroll
    for (int c = 0; c < 2; ++c)
#pragma unroll
      for (int t = 0; t < 4; ++t)
        vb[c][t] = *(const bf16x8*)&Vh[(16 * t + ln) * 72 + 32 * c + 8 * g];

    // ---- QK^T, BOTH groups in one batch (8 independent acc chains) ----
    f32x4 sA0 = (f32x4){0.f, 0.f, 0.f, 0.f};
    f32x4 sA1 = sA0, sA2 = sA0, sA3 = sA0;
    f32x4 sB0 = sA0, sB1 = sA0, sB2 = sA0, sB3 = sA0;
    __builtin_amdgcn_s_setprio(1);
    sA0 = __builtin_amdgcn_mfma_f32_16x16x32_bf16(ka[0][0], qfA0, sA0, 0, 0, 0);
    sB0 = __builtin_amdgcn_mfma_f32_16x16x32_bf16(ka[0][0], qfB0, sB0, 0, 0, 0);
    sA1 = __builtin_amdgcn_mfma_f32_16x16x32_bf16(ka[1][0], qfA0, sA1, 0, 0, 0);
    sB1 = __builtin_amdgcn_mfma_f32_16x16x32_bf16(ka[1][0], qfB0, sB1, 0, 0, 0);
    sA2 = __builtin_amdgcn_mfma_f32_16x16x32_bf16(ka[2][0], qfA0, sA2, 0, 0, 0);
    sB2 = __builtin_amdgcn_mfma_f32_16x16x32_bf16(ka[2][0], qfB0, sB2, 0, 0, 0);
    sA3 = __builtin_amdgcn_mfma_f32_16x16x32_bf16(ka[3][0], qfA0, sA3, 0, 0, 0);
    sB3 = __builtin_amdgcn_mfma_f32_16x16x32_bf16(ka[3][0], qfB0, sB3, 0, 0, 0);
    sA0 = __builtin_amdgcn_mfma_f32_16x16x32_bf16(ka[0][1], qfA1, sA0, 0, 0, 0);
    sB0 = __builtin_amdgcn_mfma_f32_16x16x32_bf16(ka[0][1], qfB1, sB0, 0, 0, 0);
    sA1 = __builtin_amdgcn_mfma_f32_16x16x32_bf16(ka[1][1], qfA1, sA1, 0, 0, 0);
    sB1 = __builtin_amdgcn_mfma_f32_16x16x32_bf16(ka[1][1], qfB1, sB1, 0, 0, 0);
    sA2 = __builtin_amdgcn_mfma_f32_16x16x32_bf16(ka[2][1], qfA1, sA2, 0, 0, 0);
    sB2 = __builtin_amdgcn_mfma_f32_16x16x32_bf16(ka[2][1], qfB1, sB2, 0, 0, 0);
    sA3 = __builtin_amdgcn_mfma_f32_16x16x32_bf16(ka[3][1], qfA1, sA3, 0, 0, 0);
    sB3 = __builtin_amdgcn_mfma_f32_16x16x32_bf16(ka[3][1], qfB1, sB3, 0, 0, 0);
    __builtin_amdgcn_s_setprio(0);

    // ---- P = exp2(S), BOTH groups (32 independent trans ops) ----
    float pA0[4], pA1[4], pA2[4], pA3[4];
    float pB0[4], pB1[4], pB2[4], pB3[4];
#pragma unroll
    for (int r = 0; r < 4; ++r) {
      pA0[r] = fast_exp2(sA0[r]);
      pA1[r] = fast_exp2(sA1[r]);
      pA2[r] = fast_exp2(sA2[r]);
      pA3[r] = fast_exp2(sA3[r]);
      pB0[r] = fast_exp2(sB0[r]);
      pB1[r] = fast_exp2(sB1[r]);
      pB2[r] = fast_exp2(sB2[r]);
      pB3[r] = fast_exp2(sB3[r]);
    }

    // ---- pack + permlane -> PV A-fragments, BOTH groups (no LDS) ----
    unsigned aa0 = cvt_pk_bf16(pA0[0], pA0[1]);
    unsigned aa2 = cvt_pk_bf16(pA1[0], pA1[1]);
    unsigned aa1 = cvt_pk_bf16(pA0[2], pA0[3]);
    unsigned aa3 = cvt_pk_bf16(pA1[2], pA1[3]);
    permswap32(aa0, aa2);
    permswap32(aa1, aa3);
    unsigned ab0 = cvt_pk_bf16(pA2[0], pA2[1]);
    unsigned ab2 = cvt_pk_bf16(pA3[0], pA3[1]);
    unsigned ab1 = cvt_pk_bf16(pA2[2], pA2[3]);
    unsigned ab3 = cvt_pk_bf16(pA3[2], pA3[3]);
    permswap32(ab0, ab2);
    permswap32(ab1, ab3);
    unsigned ba0 = cvt_pk_bf16(pB0[0], pB0[1]);
    unsigned ba2 = cvt_pk_bf16(pB1[0], pB1[1]);
    unsigned ba1 = cvt_pk_bf16(pB0[2], pB0[3]);
    unsigned ba3 = cvt_pk_bf16(pB1[2], pB1[3]);
    permswap32(ba0, ba2);
    permswap32(ba1, ba3);
    unsigned bb0 = cvt_pk_bf16(pB2[0], pB2[1]);
    unsigned bb2 = cvt_pk_bf16(pB3[0], pB3[1]);
    unsigned bb1 = cvt_pk_bf16(pB2[2], pB2[3]);
    unsigned bb3 = cvt_pk_bf16(pB3[2], pB3[3]);
    permswap32(bb0, bb2);
    permswap32(bb1, bb3);
    union { unsigned u[4]; bf16x8 v; } paA0, paA1, paB0, paB1;
    paA0.u[0] = aa0; paA0.u[1] = aa1; paA0.u[2] = aa2; paA0.u[3] = aa3;
    paA1.u[0] = ab0; paA1.u[1] = ab1; paA1.u[2] = ab2; paA1.u[3] = ab3;
    paB0.u[0] = ba0; paB0.u[1] = ba1; paB0.u[2] = ba2; paB0.u[3] = ba3;
    paB1.u[0] = bb0; paB1.u[1] = bb1; paB1.u[2] = bb2; paB1.u[3] = bb3;

    // ---- PV + denominators, BOTH groups in one MFMA batch ----
    __builtin_amdgcn_s_setprio(1);
#pragma unroll
    for (int t = 0; t < 4; ++t) {
      oaccA[t] = __builtin_amdgcn_mfma_f32_16x16x32_bf16(paA0.v, vb[0][t], oaccA[t], 0, 0, 0);
      oaccB[t] = __builtin_amdgcn_mfma_f32_16x16x32_bf16(paB0.v, vb[0][t], oaccB[t], 0, 0, 0);
      oaccA[t] = __builtin_amdgcn_mfma_f32_16x16x32_bf16(paA1.v, vb[1][t], oaccA[t], 0, 0, 0);
      oaccB[t] = __builtin_amdgcn_mfma_f32_16x16x32_bf16(paB1.v, vb[1][t], oaccB[t], 0, 0, 0);
    }
    oaccDA = __builtin_amdgcn_mfma_f32_16x16x32_bf16(paA0.v, vones, oaccDA, 0, 0, 0);
    oaccDB = __builtin_amdgcn_mfma_f32_16x16x32_bf16(paB0.v, vones, oaccDB, 0, 0, 0);
    oaccDA = __builtin_amdgcn_mfma_f32_16x16x32_bf16(paA1.v, vones, oaccDA, 0, 0, 0);
    oaccDB = __builtin_amdgcn_mfma_f32_16x16x32_bf16(paB1.v, vones, oaccDB, 0, 0, 0);
    __builtin_amdgcn_s_setprio(0);
  }

  // ---- combine halves through LDS overlay (K/V buffers are dead) ----
  float* Acc = (float*)smem;                 // [128][68] f32 = 34816B
  float* Dl  = (float*)(smem + 34816);       // [128] f32 = 512B (<=36864)
  __syncthreads();
  if (half == 0) {
#pragma unroll
    for (int t = 0; t < 4; ++t)
#pragma unroll
      for (int r = 0; r < 4; ++r) {
        Acc[(wave * 32 + 4 * g + r) * 68 + 16 * t + ln] = oaccA[t][r];
        Acc[(wave * 32 + 16 + 4 * g + r) * 68 + 16 * t + ln] = oaccB[t][r];
      }
    if (ln == 0) {
#pragma unroll
      for (int r = 0; r < 4; ++r) {
        Dl[wave * 32 + 4 * g + r] = oaccDA[r];
        Dl[wave * 32 + 16 + 4 * g + r] = oaccDB[r];
      }
    }
  }
  __syncthreads();
  if (half == 1) {
    const int b = bh >> 3, h = bh & 7;
#pragma unroll
    for (int r = 0; r < 4; ++r) {
      const int rowA = wave * 32 + 4 * g + r;
      const int rowB = rowA + 16;
      const float irA = 1.0f / (Dl[rowA] + oaccDA[r]);
      const float irB = 1.0f / (Dl[rowB] + oaccDB[r]);
      ushort* opA = O + ((size_t)(b * SEQ) + qx * 128 + rowA) * EMB + h * 64;
      ushort* opB = O + ((size_t)(b * SEQ) + qx * 128 + rowB) * EMB + h * 64;
#pragma unroll
      for (int t = 0; t < 4; ++t) {
        opA[16 * t + ln] = f2bf((Acc[rowA * 68 + 16 * t + ln] + oaccA[t][r]) * irA);
        opB[16 * t + ln] = f2bf((Acc[rowB * 68 + 16 * t + ln] + oaccB[t][r]) * irB);
      }
    }
  }
}

// ---------------------------------------------------------------------------
extern "C" void kernel_launch(void* const* d_in, const int* in_sizes, int n_in,
                              void* d_out, int out_size, void* d_ws, size_t ws_size,
                              hipStream_t stream) {
  const float* q  = (const float*)d_in[0];
  const float* wq = (const float*)d_in[1];
  const float* bq = (const float*)d_in[2];
  const float* wk = (const float*)d_in[3];
  const float* bk = (const float*)d_in[4];
  const float* wv = (const float*)d_in[5];
  const float* bv = (const float*)d_in[6];
  const float* wo = (const float*)d_in[7];
  const float* bo = (const float*)d_in[8];
  float* out = (float*)d_out;

  const size_t XSZ = (size_t)MTOT * INDIM;
  const size_t WSZ = (size_t)EMB * INDIM;
  const size_t QSZ = (size_t)BATCH * NHEADS * SEQ * DH;
  ushort* wsX = (ushort*)d_ws;
  ushort* wsW = wsX + XSZ;
  ushort* wsQ = wsW + 4 * WSZ;
  ushort* wsK = wsQ + QSZ;
  ushort* wsVT = wsK + QSZ;
  ushort* wsA = wsVT + QSZ;   // attn output bf16 [B,N,EMB]

  const dim3 blk(256);

  const int nX = (int)(XSZ / 8);       // 524288 uint4
  const int nW = (int)(WSZ / 8);       // 32768 uint4 per weight matrix
  conv_all<<<dim3((nX + 4 * nW) / 256), blk, 0, stream>>>(
      q, wq, wk, wv, wo, wsX, wsW, nX, nW);

  mfma_gemm<0><<<dim3(MTOT / 128, 1536 / 128), blk, 0, stream>>>(
      wsX, wsW, bq, bk, bv, wsQ, wsK, wsVT, nullptr);

  attn_mfma<<<dim3(512), dim3(512), 0, stream>>>(wsQ, wsK, wsVT, wsA);

  mfma_gemm<1><<<dim3(MTOT / 64, EMB / 128), blk, 0, stream>>>(
      wsA, wsW + 3 * WSZ, bo, nullptr, nullptr, nullptr, nullptr, nullptr, out);
}